// Round 1
// baseline (439.929 us; speedup 1.0000x reference)
//
#include <hip/hip_runtime.h>
#include <stdint.h>

// TransformerBlock: x:[1,4096,1024] f32 -> out f32
// DIM=1024 NH=16 HD=64 HIDDEN=2816 SEQ=4096 eps=1e-5
// Strategy: bf16 MFMA (16x16x32) for all GEMMs + flash attention; fp32 residual path.

typedef unsigned short u16;
typedef unsigned int u32;
typedef __attribute__((ext_vector_type(8))) short short8;   // 8 x bf16 (4 VGPR)
typedef __attribute__((ext_vector_type(4))) float f32x4;

#define GLD16(G, L) __builtin_amdgcn_global_load_lds( \
    (__attribute__((address_space(1))) void*)(G),      \
    (__attribute__((address_space(3))) void*)(L), 16, 0, 0)

__device__ __forceinline__ u16 f2bf(float f) {  // RNE
  u32 u = __builtin_bit_cast(u32, f);
  u32 r = u + 0x7fffu + ((u >> 16) & 1u);
  return (u16)(r >> 16);
}

// ---------- transpose + convert: in[R][C] f32 -> out[C][R] bf16 ----------
__global__ __launch_bounds__(256) void k_tc(const float* __restrict__ in,
                                            u16* __restrict__ out, int R, int C) {
  __shared__ float t[32][33];
  const int tx = threadIdx.x & 31, ty = threadIdx.x >> 5;
  const int c0 = blockIdx.x * 32, r0 = blockIdx.y * 32;
#pragma unroll
  for (int i = 0; i < 32; i += 8)
    t[ty + i][tx] = in[(size_t)(r0 + ty + i) * C + (c0 + tx)];
  __syncthreads();
#pragma unroll
  for (int i = 0; i < 32; i += 8)
    out[(size_t)(c0 + ty + i) * R + (r0 + tx)] = f2bf(t[tx][ty + i]);
}

// ---------- RMSNorm: f32 [4096][1024] -> bf16 ----------
__global__ __launch_bounds__(256) void k_rms(const float* __restrict__ x,
                                             const float* __restrict__ g,
                                             u16* __restrict__ o) {
  const int row = blockIdx.x, tid = threadIdx.x;
  const float4 v = ((const float4*)(x + (size_t)row * 1024))[tid];
  float ss = v.x * v.x + v.y * v.y + v.z * v.z + v.w * v.w;
#pragma unroll
  for (int ofs = 32; ofs > 0; ofs >>= 1) ss += __shfl_xor(ss, ofs);
  __shared__ float red[4];
  if ((tid & 63) == 0) red[tid >> 6] = ss;
  __syncthreads();
  const float s = rsqrtf((red[0] + red[1] + red[2] + red[3]) * (1.f / 1024.f) + 1e-5f);
  const float4 gv = ((const float4*)g)[tid];
  u32 lo = (u32)f2bf(v.x * s * gv.x) | ((u32)f2bf(v.y * s * gv.y) << 16);
  u32 hi = (u32)f2bf(v.z * s * gv.z) | ((u32)f2bf(v.w * s * gv.w) << 16);
  *(uint2*)(o + (size_t)row * 1024 + tid * 4) = make_uint2(lo, hi);
}

// ---------- GEMM: C[M,N] = A[M,K](bf16) @ Bt[N,K]^T(bf16) ----------
// EPI 0: bf16 out.  EPI 1: f32 out = acc + resid.
template <int EPI>
__global__ __launch_bounds__(256) void k_gemm(const u16* __restrict__ A,
                                              const u16* __restrict__ Bt,
                                              u16* __restrict__ Obf,
                                              float* __restrict__ Of,
                                              const float* __restrict__ Rz,
                                              int M, int N, int K) {
  __shared__ __align__(16) u16 As[128 * 32];
  __shared__ __align__(16) u16 Bs[128 * 32];
  const int tid = threadIdx.x;
  const int lane = tid & 63, wave = tid >> 6;
  const int wr = wave >> 1, wc = wave & 1;
  const int li = lane & 15, lg = lane >> 4;
  const int row0 = blockIdx.y * 128, col0 = blockIdx.x * 128;

  f32x4 acc[4][4] = {};
  const int sr = tid >> 2, sc = (tid & 3) * 8;
  const u16* ag = A + (size_t)(row0 + sr) * K + sc;
  const u16* bg = Bt + (size_t)(col0 + sr) * K + sc;
  u16* al = As + tid * 8;
  u16* bl = Bs + tid * 8;
  const size_t rstep = (size_t)64 * K;

  for (int k0 = 0; k0 < K; k0 += 32) {
    __syncthreads();
    GLD16(ag + k0, al);
    GLD16(ag + rstep + k0, al + 2048);
    GLD16(bg + k0, bl);
    GLD16(bg + rstep + k0, bl + 2048);
    __syncthreads();
    short8 af[4], bfr[4];
#pragma unroll
    for (int m = 0; m < 4; ++m)
      af[m] = *(const short8*)(As + (wr * 64 + m * 16 + li) * 32 + lg * 8);
#pragma unroll
    for (int n = 0; n < 4; ++n)
      bfr[n] = *(const short8*)(Bs + (wc * 64 + n * 16 + li) * 32 + lg * 8);
#pragma unroll
    for (int m = 0; m < 4; ++m)
#pragma unroll
      for (int n = 0; n < 4; ++n)
        acc[m][n] = __builtin_amdgcn_mfma_f32_16x16x32_bf16(af[m], bfr[n], acc[m][n], 0, 0, 0);
  }

#pragma unroll
  for (int m = 0; m < 4; ++m) {
    const int row = row0 + wr * 64 + m * 16 + lg * 4;
#pragma unroll
    for (int n = 0; n < 4; ++n) {
      const int col = col0 + wc * 64 + n * 16 + li;
#pragma unroll
      for (int r = 0; r < 4; ++r) {
        const size_t idx = (size_t)(row + r) * N + col;
        if (EPI == 0) Obf[idx] = f2bf(acc[m][n][r]);
        else          Of[idx] = acc[m][n][r] + Rz[idx];
      }
    }
  }
}

// ---------- fused SwiGLU FFN13: O = bf16( silu(A@B1^T) * (A@B3^T) ) ----------
__global__ __launch_bounds__(256) void k_ffn13(const u16* __restrict__ A,
                                               const u16* __restrict__ B1,
                                               const u16* __restrict__ B3,
                                               u16* __restrict__ O,
                                               int M, int N, int K) {
  __shared__ __align__(16) u16 As[128 * 32];
  __shared__ __align__(16) u16 B1s[128 * 32];
  __shared__ __align__(16) u16 B3s[128 * 32];
  const int tid = threadIdx.x;
  const int lane = tid & 63, wave = tid >> 6;
  const int wr = wave >> 1, wc = wave & 1;
  const int li = lane & 15, lg = lane >> 4;
  const int row0 = blockIdx.y * 128, col0 = blockIdx.x * 128;

  f32x4 a1[4][4] = {}, a3[4][4] = {};
  const int sr = tid >> 2, sc = (tid & 3) * 8;
  const u16* ag = A + (size_t)(row0 + sr) * K + sc;
  const u16* b1g = B1 + (size_t)(col0 + sr) * K + sc;
  const u16* b3g = B3 + (size_t)(col0 + sr) * K + sc;
  u16* al = As + tid * 8;
  u16* b1l = B1s + tid * 8;
  u16* b3l = B3s + tid * 8;
  const size_t rstep = (size_t)64 * K;

  for (int k0 = 0; k0 < K; k0 += 32) {
    __syncthreads();
    GLD16(ag + k0, al);
    GLD16(ag + rstep + k0, al + 2048);
    GLD16(b1g + k0, b1l);
    GLD16(b1g + rstep + k0, b1l + 2048);
    GLD16(b3g + k0, b3l);
    GLD16(b3g + rstep + k0, b3l + 2048);
    __syncthreads();
    short8 af[4], b1f[4], b3f[4];
#pragma unroll
    for (int m = 0; m < 4; ++m)
      af[m] = *(const short8*)(As + (wr * 64 + m * 16 + li) * 32 + lg * 8);
#pragma unroll
    for (int n = 0; n < 4; ++n) {
      b1f[n] = *(const short8*)(B1s + (wc * 64 + n * 16 + li) * 32 + lg * 8);
      b3f[n] = *(const short8*)(B3s + (wc * 64 + n * 16 + li) * 32 + lg * 8);
    }
#pragma unroll
    for (int m = 0; m < 4; ++m)
#pragma unroll
      for (int n = 0; n < 4; ++n) {
        a1[m][n] = __builtin_amdgcn_mfma_f32_16x16x32_bf16(af[m], b1f[n], a1[m][n], 0, 0, 0);
        a3[m][n] = __builtin_amdgcn_mfma_f32_16x16x32_bf16(af[m], b3f[n], a3[m][n], 0, 0, 0);
      }
  }

#pragma unroll
  for (int m = 0; m < 4; ++m) {
    const int row = row0 + wr * 64 + m * 16 + lg * 4;
#pragma unroll
    for (int n = 0; n < 4; ++n) {
      const int col = col0 + wc * 64 + n * 16 + li;
#pragma unroll
      for (int r = 0; r < 4; ++r) {
        const float g1 = a1[m][n][r], g3 = a3[m][n][r];
        const float sl = g1 / (1.f + __expf(-g1));
        O[(size_t)(row + r) * N + col] = f2bf(sl * g3);
      }
    }
  }
}

// ---------- flash attention (causal), qkv:[4096][3072] bf16, out:[4096][1024] bf16 ----------
// Block: 4 waves x 16 queries (QB=64), KV tile 64. Swapped QK^T: S^T = mfma(K, Q^T)
// -> lane holds 16 scores for query (lane&15); softmax reduce = shfl_xor 16/32.
__global__ __launch_bounds__(256) void k_attn(const u16* __restrict__ qkv,
                                              u16* __restrict__ o) {
  const int LD = 3072;
  const int bid = blockIdx.x;
  const int h = bid & 15;
  const int qb = 63 - (bid >> 4);  // heaviest q-blocks dispatched first
  const int q0 = qb * 64;
  const int tid = threadIdx.x, lane = tid & 63, w = tid >> 6;
  const int li = lane & 15, lg = lane >> 4;

  __shared__ __align__(16) u16 Ks[64][72];       // [key][dim], pad->stride 144B
  __shared__ __align__(16) u16 Vt[64][72];       // [dim][key]
  __shared__ __align__(16) u16 Ps[4][16][72];    // per-wave P [q][key]

  const int qrow = q0 + w * 16 + li;             // this lane's query (as S^T col)
  const u16* qp = qkv + (size_t)qrow * LD + h * 64;
  const short8 qf0 = *(const short8*)(qp + lg * 8);
  const short8 qf1 = *(const short8*)(qp + 32 + lg * 8);

  float msm = -1e30f, lsm = 0.f;
  f32x4 accO[4] = {};
  const int wqmax = q0 + w * 16 + 15;
  const int er = tid >> 3, ec = (tid & 7) * 8;

  for (int k0 = 0; k0 < q0 + 64; k0 += 64) {
    __syncthreads();
#pragma unroll
    for (int p = 0; p < 2; ++p) {   // stage K (row-major) and V (transposed)
      const int rr = er + p * 32;
      const short8 k8 = *(const short8*)(qkv + (size_t)(k0 + rr) * LD + 1024 + h * 64 + ec);
      *(short8*)(&Ks[rr][ec]) = k8;
      const short8 v8 = *(const short8*)(qkv + (size_t)(k0 + rr) * LD + 2048 + h * 64 + ec);
#pragma unroll
      for (int j = 0; j < 8; ++j) Vt[ec + j][rr] = (u16)v8[j];
    }
    __syncthreads();

    if (k0 <= wqmax) {  // wave-uniform
      f32x4 st[4];
#pragma unroll
      for (int f = 0; f < 4; ++f) {  // S^T[16k x 16q] = K_f @ Q^T over d=64
        const short8 ka0 = *(const short8*)(&Ks[f * 16 + li][lg * 8]);
        const short8 ka1 = *(const short8*)(&Ks[f * 16 + li][32 + lg * 8]);
        f32x4 z = {};
        z = __builtin_amdgcn_mfma_f32_16x16x32_bf16(ka0, qf0, z, 0, 0, 0);
        st[f] = __builtin_amdgcn_mfma_f32_16x16x32_bf16(ka1, qf1, z, 0, 0, 0);
      }
      float sv[16];
      float mloc = -1e30f;
#pragma unroll
      for (int f = 0; f < 4; ++f)
#pragma unroll
        for (int r = 0; r < 4; ++r) {
          const int kg = k0 + f * 16 + lg * 4 + r;
          const float xv = st[f][r] * 0.125f;
          sv[f * 4 + r] = (kg > qrow) ? -1e30f : xv;
          mloc = fmaxf(mloc, sv[f * 4 + r]);
        }
      mloc = fmaxf(mloc, __shfl_xor(mloc, 16));
      mloc = fmaxf(mloc, __shfl_xor(mloc, 32));
      const float mnew = fmaxf(msm, mloc);
      const float alpha = __expf(msm - mnew);
      float psum = 0.f;
#pragma unroll
      for (int f = 0; f < 4; ++f) {
        const float p0 = __expf(sv[f * 4 + 0] - mnew);
        const float p1 = __expf(sv[f * 4 + 1] - mnew);
        const float p2 = __expf(sv[f * 4 + 2] - mnew);
        const float p3 = __expf(sv[f * 4 + 3] - mnew);
        psum += (p0 + p1) + (p2 + p3);
        const u32 lo = (u32)f2bf(p0) | ((u32)f2bf(p1) << 16);
        const u32 hi = (u32)f2bf(p2) | ((u32)f2bf(p3) << 16);
        *(uint2*)(&Ps[w][li][f * 16 + lg * 4]) = make_uint2(lo, hi);
      }
      psum += __shfl_xor(psum, 16);
      psum += __shfl_xor(psum, 32);
      lsm = lsm * alpha + psum;
      msm = mnew;
#pragma unroll
      for (int r = 0; r < 4; ++r) {   // rescale O (row q = lg*4+r; alpha lives at lane q)
        const float ar = __shfl(alpha, lg * 4 + r);
#pragma unroll
        for (int n = 0; n < 4; ++n) accO[n][r] *= ar;
      }
#pragma unroll
      for (int kk = 0; kk < 2; ++kk) {  // O[16q x 64d] += P @ V
        const short8 pf = *(const short8*)(&Ps[w][li][kk * 32 + lg * 8]);
#pragma unroll
        for (int n = 0; n < 4; ++n) {
          const short8 vf = *(const short8*)(&Vt[n * 16 + li][kk * 32 + lg * 8]);
          accO[n] = __builtin_amdgcn_mfma_f32_16x16x32_bf16(pf, vf, accO[n], 0, 0, 0);
        }
      }
    }
  }
#pragma unroll
  for (int r = 0; r < 4; ++r) {
    const float linv = 1.f / __shfl(lsm, lg * 4 + r);
    const int row = q0 + w * 16 + lg * 4 + r;
#pragma unroll
    for (int n = 0; n < 4; ++n)
      o[(size_t)row * 1024 + h * 64 + n * 16 + li] = f2bf(accO[n][r] * linv);
  }
}

extern "C" void kernel_launch(void* const* d_in, const int* in_sizes, int n_in,
                              void* d_out, int out_size, void* d_ws, size_t ws_size,
                              hipStream_t stream) {
  const float* x  = (const float*)d_in[0];
  const float* wq = (const float*)d_in[1];
  const float* wk = (const float*)d_in[2];
  const float* wv = (const float*)d_in[3];
  const float* wo = (const float*)d_in[4];
  const float* w1 = (const float*)d_in[5];
  const float* w2 = (const float*)d_in[6];   // note: w2 before w3 in dict order
  const float* w3 = (const float*)d_in[7];
  const float* ga = (const float*)d_in[8];
  const float* gf = (const float*)d_in[9];
  float* out = (float*)d_out;

  char* p = (char*)d_ws;
  auto take = [&](size_t n) { char* r = p; p += (n + 255) & ~(size_t)255; return r; };
  u16* wqkv_t = (u16*)take(3072ull * 1024 * 2);  // [3072][1024] = [wq^T; wk^T; wv^T]
  u16* wo_t   = (u16*)take(1024ull * 1024 * 2);
  u16* w1_t   = (u16*)take(2816ull * 1024 * 2);
  u16* w3_t   = (u16*)take(2816ull * 1024 * 2);
  u16* w2_t   = (u16*)take(1024ull * 2816 * 2);
  u16* xn     = (u16*)take(4096ull * 1024 * 2);
  u16* qkvb   = (u16*)take(4096ull * 3072 * 2);
  u16* atn    = (u16*)take(4096ull * 1024 * 2);
  float* hb   = (float*)take(4096ull * 1024 * 4);
  u16* hn     = (u16*)take(4096ull * 1024 * 2);
  u16* ffb    = (u16*)take(4096ull * 2816 * 2);
  // total ws use ~116 MB

  k_tc<<<dim3(32, 32), 256, 0, stream>>>(wq, wqkv_t, 1024, 1024);
  k_tc<<<dim3(32, 32), 256, 0, stream>>>(wk, wqkv_t + 1024ull * 1024, 1024, 1024);
  k_tc<<<dim3(32, 32), 256, 0, stream>>>(wv, wqkv_t + 2048ull * 1024, 1024, 1024);
  k_tc<<<dim3(32, 32), 256, 0, stream>>>(wo, wo_t, 1024, 1024);
  k_tc<<<dim3(88, 32), 256, 0, stream>>>(w1, w1_t, 1024, 2816);
  k_tc<<<dim3(88, 32), 256, 0, stream>>>(w3, w3_t, 1024, 2816);
  k_tc<<<dim3(32, 88), 256, 0, stream>>>(w2, w2_t, 2816, 1024);

  k_rms<<<4096, 256, 0, stream>>>(x, ga, xn);
  k_gemm<0><<<dim3(24, 32), 256, 0, stream>>>(xn, wqkv_t, qkvb, nullptr, nullptr, 4096, 3072, 1024);
  k_attn<<<1024, 256, 0, stream>>>(qkvb, atn);
  k_gemm<1><<<dim3(8, 32), 256, 0, stream>>>(atn, wo_t, nullptr, hb, x, 4096, 1024, 1024);
  k_rms<<<4096, 256, 0, stream>>>(hb, gf, hn);
  k_ffn13<<<dim3(22, 32), 256, 0, stream>>>(hn, w1_t, w3_t, ffb, 4096, 2816, 1024);
  k_gemm<1><<<dim3(8, 32), 256, 0, stream>>>(ffb, w2_t, nullptr, out, hb, 4096, 1024, 2816);
}

// Round 2
// 390.099 us; speedup vs baseline: 1.1277x; 1.1277x over previous
//
#include <hip/hip_runtime.h>
#include <stdint.h>

// TransformerBlock: x:[1,4096,1024] f32 -> out f32
// DIM=1024 NH=16 HD=64 HIDDEN=2816 SEQ=4096 eps=1e-5
// bf16 MFMA (16x16x32) GEMMs + flash attention (O^T form, swizzled LDS); fp32 residual path.

typedef unsigned short u16;
typedef unsigned int u32;
typedef __attribute__((ext_vector_type(8))) short short8;   // 8 x bf16 (4 VGPR)
typedef __attribute__((ext_vector_type(4))) float f32x4;

#define GLD16(G, L) __builtin_amdgcn_global_load_lds( \
    (__attribute__((address_space(1))) void*)(G),      \
    (__attribute__((address_space(3))) void*)(L), 16, 0, 0)

__device__ __forceinline__ u16 f2bf(float f) {  // RNE
  u32 u = __builtin_bit_cast(u32, f);
  u32 r = u + 0x7fffu + ((u >> 16) & 1u);
  return (u16)(r >> 16);
}
__device__ __forceinline__ float bf2f(u16 b) {
  u32 u = (u32)b << 16;
  return __builtin_bit_cast(float, u);
}

// ---------- transpose + convert: in[R][C] f32 -> out[C][R] bf16 ----------
__global__ __launch_bounds__(256) void k_tc(const float* __restrict__ in,
                                            u16* __restrict__ out, int R, int C) {
  __shared__ float t[32][33];
  const int tx = threadIdx.x & 31, ty = threadIdx.x >> 5;
  const int c0 = blockIdx.x * 32, r0 = blockIdx.y * 32;
#pragma unroll
  for (int i = 0; i < 32; i += 8)
    t[ty + i][tx] = in[(size_t)(r0 + ty + i) * C + (c0 + tx)];
  __syncthreads();
#pragma unroll
  for (int i = 0; i < 32; i += 8)
    out[(size_t)(c0 + ty + i) * R + (r0 + tx)] = f2bf(t[tx][ty + i]);
}

// ---------- RMSNorm: f32 [4096][1024] -> bf16 ----------
__global__ __launch_bounds__(256) void k_rms(const float* __restrict__ x,
                                             const float* __restrict__ g,
                                             u16* __restrict__ o) {
  const int row = blockIdx.x, tid = threadIdx.x;
  const float4 v = ((const float4*)(x + (size_t)row * 1024))[tid];
  float ss = v.x * v.x + v.y * v.y + v.z * v.z + v.w * v.w;
#pragma unroll
  for (int ofs = 32; ofs > 0; ofs >>= 1) ss += __shfl_xor(ss, ofs);
  __shared__ float red[4];
  if ((tid & 63) == 0) red[tid >> 6] = ss;
  __syncthreads();
  const float s = rsqrtf((red[0] + red[1] + red[2] + red[3]) * (1.f / 1024.f) + 1e-5f);
  const float4 gv = ((const float4*)g)[tid];
  u32 lo = (u32)f2bf(v.x * s * gv.x) | ((u32)f2bf(v.y * s * gv.y) << 16);
  u32 hi = (u32)f2bf(v.z * s * gv.z) | ((u32)f2bf(v.w * s * gv.w) << 16);
  *(uint2*)(o + (size_t)row * 1024 + tid * 4) = make_uint2(lo, hi);
}

// ---------- GEMM: C[M,N] = A[M,K](bf16) @ Bt[N,K]^T(bf16) ----------
// EPI 0: bf16 out.  EPI 1: f32 out = acc + resid.
template <int EPI>
__global__ __launch_bounds__(256) void k_gemm(const u16* __restrict__ A,
                                              const u16* __restrict__ Bt,
                                              u16* __restrict__ Obf,
                                              float* __restrict__ Of,
                                              const float* __restrict__ Rz,
                                              int M, int N, int K) {
  __shared__ __align__(16) u16 As[128 * 32];
  __shared__ __align__(16) u16 Bs[128 * 32];
  const int tid = threadIdx.x;
  const int lane = tid & 63, wave = tid >> 6;
  const int wr = wave >> 1, wc = wave & 1;
  const int li = lane & 15, lg = lane >> 4;
  const int row0 = blockIdx.y * 128, col0 = blockIdx.x * 128;

  f32x4 acc[4][4] = {};
  const int sr = tid >> 2, sc = (tid & 3) * 8;
  const u16* ag = A + (size_t)(row0 + sr) * K + sc;
  const u16* bg = Bt + (size_t)(col0 + sr) * K + sc;
  u16* al = As + tid * 8;
  u16* bl = Bs + tid * 8;
  const size_t rstep = (size_t)64 * K;

  for (int k0 = 0; k0 < K; k0 += 32) {
    __syncthreads();
    GLD16(ag + k0, al);
    GLD16(ag + rstep + k0, al + 2048);
    GLD16(bg + k0, bl);
    GLD16(bg + rstep + k0, bl + 2048);
    __syncthreads();
    short8 af[4], bfr[4];
#pragma unroll
    for (int m = 0; m < 4; ++m)
      af[m] = *(const short8*)(As + (wr * 64 + m * 16 + li) * 32 + lg * 8);
#pragma unroll
    for (int n = 0; n < 4; ++n)
      bfr[n] = *(const short8*)(Bs + (wc * 64 + n * 16 + li) * 32 + lg * 8);
#pragma unroll
    for (int m = 0; m < 4; ++m)
#pragma unroll
      for (int n = 0; n < 4; ++n)
        acc[m][n] = __builtin_amdgcn_mfma_f32_16x16x32_bf16(af[m], bfr[n], acc[m][n], 0, 0, 0);
  }

#pragma unroll
  for (int m = 0; m < 4; ++m) {
    const int row = row0 + wr * 64 + m * 16 + lg * 4;
#pragma unroll
    for (int n = 0; n < 4; ++n) {
      const int col = col0 + wc * 64 + n * 16 + li;
#pragma unroll
      for (int r = 0; r < 4; ++r) {
        const size_t idx = (size_t)(row + r) * N + col;
        if (EPI == 0) Obf[idx] = f2bf(acc[m][n][r]);
        else          Of[idx] = acc[m][n][r] + Rz[idx];
      }
    }
  }
}

// ---------- fused SwiGLU FFN13: O = bf16( silu(A@B1^T) * (A@B3^T) ) ----------
__global__ __launch_bounds__(256) void k_ffn13(const u16* __restrict__ A,
                                               const u16* __restrict__ B1,
                                               const u16* __restrict__ B3,
                                               u16* __restrict__ O,
                                               int M, int N, int K) {
  __shared__ __align__(16) u16 As[128 * 32];
  __shared__ __align__(16) u16 B1s[128 * 32];
  __shared__ __align__(16) u16 B3s[128 * 32];
  const int tid = threadIdx.x;
  const int lane = tid & 63, wave = tid >> 6;
  const int wr = wave >> 1, wc = wave & 1;
  const int li = lane & 15, lg = lane >> 4;
  const int row0 = blockIdx.y * 128, col0 = blockIdx.x * 128;

  f32x4 a1[4][4] = {}, a3[4][4] = {};
  const int sr = tid >> 2, sc = (tid & 3) * 8;
  const u16* ag = A + (size_t)(row0 + sr) * K + sc;
  const u16* b1g = B1 + (size_t)(col0 + sr) * K + sc;
  const u16* b3g = B3 + (size_t)(col0 + sr) * K + sc;
  u16* al = As + tid * 8;
  u16* b1l = B1s + tid * 8;
  u16* b3l = B3s + tid * 8;
  const size_t rstep = (size_t)64 * K;

  for (int k0 = 0; k0 < K; k0 += 32) {
    __syncthreads();
    GLD16(ag + k0, al);
    GLD16(ag + rstep + k0, al + 2048);
    GLD16(b1g + k0, b1l);
    GLD16(b1g + rstep + k0, b1l + 2048);
    GLD16(b3g + k0, b3l);
    GLD16(b3g + rstep + k0, b3l + 2048);
    __syncthreads();
    short8 af[4], b1f[4], b3f[4];
#pragma unroll
    for (int m = 0; m < 4; ++m)
      af[m] = *(const short8*)(As + (wr * 64 + m * 16 + li) * 32 + lg * 8);
#pragma unroll
    for (int n = 0; n < 4; ++n) {
      b1f[n] = *(const short8*)(B1s + (wc * 64 + n * 16 + li) * 32 + lg * 8);
      b3f[n] = *(const short8*)(B3s + (wc * 64 + n * 16 + li) * 32 + lg * 8);
    }
#pragma unroll
    for (int m = 0; m < 4; ++m)
#pragma unroll
      for (int n = 0; n < 4; ++n) {
        a1[m][n] = __builtin_amdgcn_mfma_f32_16x16x32_bf16(af[m], b1f[n], a1[m][n], 0, 0, 0);
        a3[m][n] = __builtin_amdgcn_mfma_f32_16x16x32_bf16(af[m], b3f[n], a3[m][n], 0, 0, 0);
      }
  }

#pragma unroll
  for (int m = 0; m < 4; ++m) {
    const int row = row0 + wr * 64 + m * 16 + lg * 4;
#pragma unroll
    for (int n = 0; n < 4; ++n) {
      const int col = col0 + wc * 64 + n * 16 + li;
#pragma unroll
      for (int r = 0; r < 4; ++r) {
        const float g1 = a1[m][n][r], g3 = a3[m][n][r];
        const float sl = g1 / (1.f + __expf(-g1));
        O[(size_t)(row + r) * N + col] = f2bf(sl * g3);
      }
    }
  }
}

// ---------- flash attention (causal), qkv:[4096][3072] bf16, out:[4096][1024] bf16 ----------
// 4 waves x 16 queries, KV tile 64. S^T = mfma(K, Q^T) -> per-lane stats for query li.
// O^T = mfma(V^T, P^T) -> alpha/linv lane-local, packed output stores.
// K: global_load_lds with pre-swizzled source; V: reg-transposed, swizzled b128 writes.
// Swizzle: byte_in_row ^= (row&7)<<4 on all 128B-stride LDS tiles.
__global__ __launch_bounds__(256) void k_attn(const u16* __restrict__ qkv,
                                              u16* __restrict__ o) {
  const int LD = 3072;
  const int h = blockIdx.x & 15;
  const int qb = 63 - (blockIdx.x >> 4);  // heaviest q-blocks first
  const int q0 = qb * 64;
  const int tid = threadIdx.x, lane = tid & 63, w = tid >> 6;
  const int li = lane & 15, lg = lane >> 4;
  const int swzB = (li & 7) << 4;         // byte swizzle key for rows == li (mod 8)

  __shared__ __align__(16) u16 Ks[64 * 64];   // [key][d], swizzled
  __shared__ __align__(16) u16 Vt[64 * 64];   // [d][key], swizzled
  __shared__ __align__(16) u16 Ps[4 * 16 * 64]; // per-wave [q][key], swizzled

  // ---- Q fragment (pre-scaled by 1/sqrt(64), exact in bf16) ----
  const int qrow = q0 + w * 16 + li;
  const u16* qp = qkv + (size_t)qrow * LD + h * 64;
  short8 qf0, qf1;
#pragma unroll
  for (int j = 0; j < 8; ++j) {
    qf0[j] = (short)(__builtin_bit_cast(u32, bf2f(qp[lg * 8 + j]) * 0.125f) >> 16);
    qf1[j] = (short)(__builtin_bit_cast(u32, bf2f(qp[32 + lg * 8 + j]) * 0.125f) >> 16);
  }

  // ---- K staging setup: global_load_lds, pre-swizzled source column ----
  const int krow = w * 16 + (lane >> 3);                 // p=0 row; p=1 adds 8
  const int kcol = ((lane & 7) ^ (lane >> 3)) * 8;       // swizzled source col (u16)
  const u16* kg = qkv + 1024 + h * 64 + kcol;            // + (k0+row)*LD
  u16* klds0 = Ks + (w * 2 + 0) * 512 + lane * 8;
  u16* klds1 = Ks + (w * 2 + 1) * 512 + lane * 8;

  // ---- V staging setup: 8 u32 column loads -> 2 swizzled b128 writes ----
  const int vd0 = (tid & 31) * 2;
  const int vkq = tid >> 5;                              // 0..7, 8 keys each
  const u16* vg = qkv + 2048 + h * 64 + vd0;             // + (k0+vkq*8+i)*LD
  u32* vl0 = (u32*)(Vt + (size_t)vd0 * 64 + (((vkq * 16) ^ ((vd0 & 7) << 4)) >> 1));
  u32* vl1 = (u32*)(Vt + (size_t)(vd0 + 1) * 64 + (((vkq * 16) ^ (((vd0 + 1) & 7) << 4)) >> 1));

  u16* pw = Ps + w * 1024 + li * 64;                     // this lane's P row base

  float msm = -1e30f, lsm = 0.f;
  f32x4 accO[4] = {};
  u32 vld[8];

  // prologue: V loads for tile 0
  {
    const u16* vp = vg;  // k0 = 0
#pragma unroll
    for (int i = 0; i < 8; ++i) vld[i] = *(const u32*)(vp + (size_t)(vkq * 8 + i) * LD);
  }

  for (int k0 = 0; k0 <= q0; k0 += 64) {
    __syncthreads();
    // K: 2 async global->LDS (linear dest, source pre-swizzled)
    GLD16(kg + (size_t)(k0 + krow) * LD, klds0);
    GLD16(kg + (size_t)(k0 + krow + 8) * LD, klds1);
    // V: pack the prefetched columns and write swizzled b128
    {
      u32 lo0 = (vld[0] & 0xffffu) | (vld[1] << 16);
      u32 lo1 = (vld[2] & 0xffffu) | (vld[3] << 16);
      u32 lo2 = (vld[4] & 0xffffu) | (vld[5] << 16);
      u32 lo3 = (vld[6] & 0xffffu) | (vld[7] << 16);
      u32 hi0 = (vld[0] >> 16) | (vld[1] & 0xffff0000u);
      u32 hi1 = (vld[2] >> 16) | (vld[3] & 0xffff0000u);
      u32 hi2 = (vld[4] >> 16) | (vld[5] & 0xffff0000u);
      u32 hi3 = (vld[6] >> 16) | (vld[7] & 0xffff0000u);
      *(uint4*)vl0 = make_uint4(lo0, lo1, lo2, lo3);
      *(uint4*)vl1 = make_uint4(hi0, hi1, hi2, hi3);
    }
    __syncthreads();
    // prefetch next tile's V columns (in flight during compute)
    if (k0 + 64 <= q0) {
      const u16* vp = vg + (size_t)(k0 + 64) * LD;
#pragma unroll
      for (int i = 0; i < 8; ++i) vld[i] = *(const u32*)(vp + (size_t)(vkq * 8 + i) * LD);
    }

    // ---- QK^T: S^T[key][q] ----
    f32x4 st[4];
#pragma unroll
    for (int f = 0; f < 4; ++f) {
      const u16* kp = Ks + (size_t)(f * 16 + li) * 64;
      const short8 ka0 = *(const short8*)(kp + (((lg * 16) ^ swzB) >> 1));
      const short8 ka1 = *(const short8*)(kp + (((64 + lg * 16) ^ swzB) >> 1));
      f32x4 z = {};
      z = __builtin_amdgcn_mfma_f32_16x16x32_bf16(ka0, qf0, z, 0, 0, 0);
      st[f] = __builtin_amdgcn_mfma_f32_16x16x32_bf16(ka1, qf1, st[f] = z, 0, 0, 0);
    }

    // ---- online softmax (stats lane-local: query = li) ----
    float sv[16];
    float mloc = -1e30f;
    if (k0 < q0) {  // fully unmasked tile
#pragma unroll
      for (int f = 0; f < 4; ++f)
#pragma unroll
        for (int r = 0; r < 4; ++r) {
          sv[f * 4 + r] = st[f][r];
          mloc = fmaxf(mloc, sv[f * 4 + r]);
        }
    } else {        // diagonal tile
#pragma unroll
      for (int f = 0; f < 4; ++f)
#pragma unroll
        for (int r = 0; r < 4; ++r) {
          const int kg2 = k0 + f * 16 + lg * 4 + r;
          sv[f * 4 + r] = (kg2 > qrow) ? -1e30f : st[f][r];
          mloc = fmaxf(mloc, sv[f * 4 + r]);
        }
    }
    mloc = fmaxf(mloc, __shfl_xor(mloc, 16));
    mloc = fmaxf(mloc, __shfl_xor(mloc, 32));
    const float mnew = fmaxf(msm, mloc);
    const float alpha = __expf(msm - mnew);
    float psum = 0.f;
#pragma unroll
    for (int f = 0; f < 4; ++f) {
      const float p0 = __expf(sv[f * 4 + 0] - mnew);
      const float p1 = __expf(sv[f * 4 + 1] - mnew);
      const float p2 = __expf(sv[f * 4 + 2] - mnew);
      const float p3 = __expf(sv[f * 4 + 3] - mnew);
      psum += (p0 + p1) + (p2 + p3);
      const u32 lo = (u32)f2bf(p0) | ((u32)f2bf(p1) << 16);
      const u32 hi = (u32)f2bf(p2) | ((u32)f2bf(p3) << 16);
      *(uint2*)(pw + (((f * 32 + lg * 8) ^ swzB) >> 1)) = make_uint2(lo, hi);
    }
    psum += __shfl_xor(psum, 16);
    psum += __shfl_xor(psum, 32);
    lsm = lsm * alpha + psum;
    msm = mnew;
#pragma unroll
    for (int n = 0; n < 4; ++n) {   // alpha lane-local in O^T form
      accO[n][0] *= alpha; accO[n][1] *= alpha;
      accO[n][2] *= alpha; accO[n][3] *= alpha;
    }

    // ---- PV: O^T[d][q] += V^T @ P^T ----
#pragma unroll
    for (int kk = 0; kk < 2; ++kk) {
      const int cofs = ((kk * 64 + lg * 16) ^ swzB) >> 1;
      const short8 pf = *(const short8*)(pw + cofs);
#pragma unroll
      for (int n = 0; n < 4; ++n) {
        const short8 vf = *(const short8*)(Vt + (size_t)(n * 16 + li) * 64 + cofs);
        accO[n] = __builtin_amdgcn_mfma_f32_16x16x32_bf16(vf, pf, accO[n], 0, 0, 0);
      }
    }
  }

  // ---- epilogue: O^T -> o[q][h*64+d], packed 8B stores ----
  const float linv = 1.f / lsm;
  u16* op = o + (size_t)(q0 + w * 16 + li) * 1024 + h * 64;
#pragma unroll
  for (int n = 0; n < 4; ++n) {
    const u32 lo = (u32)f2bf(accO[n][0] * linv) | ((u32)f2bf(accO[n][1] * linv) << 16);
    const u32 hi = (u32)f2bf(accO[n][2] * linv) | ((u32)f2bf(accO[n][3] * linv) << 16);
    *(uint2*)(op + n * 16 + lg * 4) = make_uint2(lo, hi);
  }
}

extern "C" void kernel_launch(void* const* d_in, const int* in_sizes, int n_in,
                              void* d_out, int out_size, void* d_ws, size_t ws_size,
                              hipStream_t stream) {
  const float* x  = (const float*)d_in[0];
  const float* wq = (const float*)d_in[1];
  const float* wk = (const float*)d_in[2];
  const float* wv = (const float*)d_in[3];
  const float* wo = (const float*)d_in[4];
  const float* w1 = (const float*)d_in[5];
  const float* w2 = (const float*)d_in[6];   // w2 before w3 in dict order
  const float* w3 = (const float*)d_in[7];
  const float* ga = (const float*)d_in[8];
  const float* gf = (const float*)d_in[9];
  float* out = (float*)d_out;

  char* p = (char*)d_ws;
  auto take = [&](size_t n) { char* r = p; p += (n + 255) & ~(size_t)255; return r; };
  u16* wqkv_t = (u16*)take(3072ull * 1024 * 2);  // [wq^T; wk^T; wv^T]
  u16* wo_t   = (u16*)take(1024ull * 1024 * 2);
  u16* w1_t   = (u16*)take(2816ull * 1024 * 2);
  u16* w3_t   = (u16*)take(2816ull * 1024 * 2);
  u16* w2_t   = (u16*)take(1024ull * 2816 * 2);
  u16* xn     = (u16*)take(4096ull * 1024 * 2);
  u16* qkvb   = (u16*)take(4096ull * 3072 * 2);
  u16* atn    = (u16*)take(4096ull * 1024 * 2);
  float* hb   = (float*)take(4096ull * 1024 * 4);
  u16* hn     = (u16*)take(4096ull * 1024 * 2);
  u16* ffb    = (u16*)take(4096ull * 2816 * 2);

  k_tc<<<dim3(32, 32), 256, 0, stream>>>(wq, wqkv_t, 1024, 1024);
  k_tc<<<dim3(32, 32), 256, 0, stream>>>(wk, wqkv_t + 1024ull * 1024, 1024, 1024);
  k_tc<<<dim3(32, 32), 256, 0, stream>>>(wv, wqkv_t + 2048ull * 1024, 1024, 1024);
  k_tc<<<dim3(32, 32), 256, 0, stream>>>(wo, wo_t, 1024, 1024);
  k_tc<<<dim3(88, 32), 256, 0, stream>>>(w1, w1_t, 1024, 2816);
  k_tc<<<dim3(88, 32), 256, 0, stream>>>(w3, w3_t, 1024, 2816);
  k_tc<<<dim3(32, 88), 256, 0, stream>>>(w2, w2_t, 2816, 1024);

  k_rms<<<4096, 256, 0, stream>>>(x, ga, xn);
  k_gemm<0><<<dim3(24, 32), 256, 0, stream>>>(xn, wqkv_t, qkvb, nullptr, nullptr, 4096, 3072, 1024);
  k_attn<<<1024, 256, 0, stream>>>(qkvb, atn);
  k_gemm<1><<<dim3(8, 32), 256, 0, stream>>>(atn, wo_t, nullptr, hb, x, 4096, 1024, 1024);
  k_rms<<<4096, 256, 0, stream>>>(hb, gf, hn);
  k_ffn13<<<dim3(22, 32), 256, 0, stream>>>(hn, w1_t, w3_t, ffb, 4096, 2816, 1024);
  k_gemm<1><<<dim3(8, 32), 256, 0, stream>>>(ffb, w2_t, nullptr, out, hb, 4096, 1024, 2816);
}

// Round 3
// 322.905 us; speedup vs baseline: 1.3624x; 1.2081x over previous
//
#include <hip/hip_runtime.h>
#include <stdint.h>

// TransformerBlock: x:[1,4096,1024] f32 -> out f32
// DIM=1024 NH=16 HD=64 HIDDEN=2816 SEQ=4096 eps=1e-5
// bf16 MFMA (16x16x32) GEMMs + flash attention (O^T form, swizzled LDS); fp32 residual path.

typedef unsigned short u16;
typedef unsigned int u32;
typedef __attribute__((ext_vector_type(8))) short short8;   // 8 x bf16 (4 VGPR)
typedef __attribute__((ext_vector_type(4))) float f32x4;

#define GLD16(G, L) __builtin_amdgcn_global_load_lds( \
    (__attribute__((address_space(1))) void*)(G),      \
    (__attribute__((address_space(3))) void*)(L), 16, 0, 0)

__device__ __forceinline__ u16 f2bf(float f) {  // RNE
  u32 u = __builtin_bit_cast(u32, f);
  u32 r = u + 0x7fffu + ((u >> 16) & 1u);
  return (u16)(r >> 16);
}
__device__ __forceinline__ float bf2f(u16 b) {
  u32 u = (u32)b << 16;
  return __builtin_bit_cast(float, u);
}

// ---------- transpose + convert: in[R][C] f32 -> out[C][R] bf16, z-muxed ----------
__global__ __launch_bounds__(256) void k_tc4(const float* __restrict__ s0,
                                             const float* __restrict__ s1,
                                             const float* __restrict__ s2,
                                             const float* __restrict__ s3,
                                             u16* __restrict__ out, int R, int C) {
  const int z = blockIdx.z;
  const float* in = (z == 0) ? s0 : (z == 1) ? s1 : (z == 2) ? s2 : s3;
  u16* o = out + (size_t)z * R * C;
  __shared__ float t[32][33];
  const int tx = threadIdx.x & 31, ty = threadIdx.x >> 5;
  const int c0 = blockIdx.x * 32, r0 = blockIdx.y * 32;
#pragma unroll
  for (int i = 0; i < 32; i += 8)
    t[ty + i][tx] = in[(size_t)(r0 + ty + i) * C + (c0 + tx)];
  __syncthreads();
#pragma unroll
  for (int i = 0; i < 32; i += 8)
    o[(size_t)(c0 + ty + i) * R + (r0 + tx)] = f2bf(t[tx][ty + i]);
}

// ---------- RMSNorm: f32 [4096][1024] -> bf16 ----------
__global__ __launch_bounds__(256) void k_rms(const float* __restrict__ x,
                                             const float* __restrict__ g,
                                             u16* __restrict__ o) {
  const int row = blockIdx.x, tid = threadIdx.x;
  const float4 v = ((const float4*)(x + (size_t)row * 1024))[tid];
  float ss = v.x * v.x + v.y * v.y + v.z * v.z + v.w * v.w;
#pragma unroll
  for (int ofs = 32; ofs > 0; ofs >>= 1) ss += __shfl_xor(ss, ofs);
  __shared__ float red[4];
  if ((tid & 63) == 0) red[tid >> 6] = ss;
  __syncthreads();
  const float s = rsqrtf((red[0] + red[1] + red[2] + red[3]) * (1.f / 1024.f) + 1e-5f);
  const float4 gv = ((const float4*)g)[tid];
  u32 lo = (u32)f2bf(v.x * s * gv.x) | ((u32)f2bf(v.y * s * gv.y) << 16);
  u32 hi = (u32)f2bf(v.z * s * gv.z) | ((u32)f2bf(v.w * s * gv.w) << 16);
  *(uint2*)(o + (size_t)row * 1024 + tid * 4) = make_uint2(lo, hi);
}

// ---------- GEMM: C[M,N] = A[M,K](bf16) @ Bt[N,K]^T(bf16), tile 128xTN ----------
// EPI 0: bf16 out.  EPI 1: f32 out = acc + resid.
template <int EPI, int TN>
__global__ __launch_bounds__(256) void k_gemm(const u16* __restrict__ A,
                                              const u16* __restrict__ Bt,
                                              u16* __restrict__ Obf,
                                              float* __restrict__ Of,
                                              const float* __restrict__ Rz,
                                              int M, int N, int K) {
  constexpr int NFR = TN / 32;             // n-frags per wave (waves 2x2)
  __shared__ __align__(16) u16 As[128 * 32];
  __shared__ __align__(16) u16 Bs[TN * 32];
  const int tid = threadIdx.x;
  const int lane = tid & 63, wave = tid >> 6;
  const int wr = wave >> 1, wc = wave & 1;
  const int li = lane & 15, lg = lane >> 4;
  const int row0 = blockIdx.y * 128, col0 = blockIdx.x * TN;

  f32x4 acc[4][NFR] = {};
  const int sr = tid >> 2, sc = (tid & 3) * 8;
  const u16* ag = A + (size_t)(row0 + sr) * K + sc;
  const u16* bg = Bt + (size_t)(col0 + sr) * K + sc;
  u16* al = As + tid * 8;
  u16* bl = Bs + tid * 8;
  const size_t rstep = (size_t)64 * K;

  for (int k0 = 0; k0 < K; k0 += 32) {
    __syncthreads();
    GLD16(ag + k0, al);
    GLD16(ag + rstep + k0, al + 2048);
    GLD16(bg + k0, bl);
    if constexpr (TN == 128) GLD16(bg + rstep + k0, bl + 2048);
    __syncthreads();
    short8 af[4], bfr[NFR];
#pragma unroll
    for (int m = 0; m < 4; ++m)
      af[m] = *(const short8*)(As + (wr * 64 + m * 16 + li) * 32 + lg * 8);
#pragma unroll
    for (int n = 0; n < NFR; ++n)
      bfr[n] = *(const short8*)(Bs + (wc * (TN / 2) + n * 16 + li) * 32 + lg * 8);
#pragma unroll
    for (int m = 0; m < 4; ++m)
#pragma unroll
      for (int n = 0; n < NFR; ++n)
        acc[m][n] = __builtin_amdgcn_mfma_f32_16x16x32_bf16(af[m], bfr[n], acc[m][n], 0, 0, 0);
  }

#pragma unroll
  for (int m = 0; m < 4; ++m) {
    const int row = row0 + wr * 64 + m * 16 + lg * 4;
#pragma unroll
    for (int n = 0; n < NFR; ++n) {
      const int col = col0 + wc * (TN / 2) + n * 16 + li;
#pragma unroll
      for (int r = 0; r < 4; ++r) {
        const size_t idx = (size_t)(row + r) * N + col;
        if (EPI == 0) Obf[idx] = f2bf(acc[m][n][r]);
        else          Of[idx] = acc[m][n][r] + Rz[idx];
      }
    }
  }
}

// ---------- fused SwiGLU FFN13: O = bf16( silu(A@B1^T) * (A@B3^T) ), tile 128x64 ----------
__global__ __launch_bounds__(256) void k_ffn13(const u16* __restrict__ A,
                                               const u16* __restrict__ B1,
                                               const u16* __restrict__ B3,
                                               u16* __restrict__ O,
                                               int M, int N, int K) {
  __shared__ __align__(16) u16 As[128 * 32];
  __shared__ __align__(16) u16 B1s[64 * 32];
  __shared__ __align__(16) u16 B3s[64 * 32];
  const int tid = threadIdx.x;
  const int lane = tid & 63, wave = tid >> 6;
  const int wr = wave >> 1, wc = wave & 1;
  const int li = lane & 15, lg = lane >> 4;
  const int row0 = blockIdx.y * 128, col0 = blockIdx.x * 64;

  f32x4 a1[4][2] = {}, a3[4][2] = {};
  const int sr = tid >> 2, sc = (tid & 3) * 8;
  const u16* ag = A + (size_t)(row0 + sr) * K + sc;
  const u16* b1g = B1 + (size_t)(col0 + sr) * K + sc;
  const u16* b3g = B3 + (size_t)(col0 + sr) * K + sc;
  u16* al = As + tid * 8;
  u16* b1l = B1s + tid * 8;
  u16* b3l = B3s + tid * 8;
  const size_t rstep = (size_t)64 * K;

  for (int k0 = 0; k0 < K; k0 += 32) {
    __syncthreads();
    GLD16(ag + k0, al);
    GLD16(ag + rstep + k0, al + 2048);
    GLD16(b1g + k0, b1l);
    GLD16(b3g + k0, b3l);
    __syncthreads();
    short8 af[4], b1f[2], b3f[2];
#pragma unroll
    for (int m = 0; m < 4; ++m)
      af[m] = *(const short8*)(As + (wr * 64 + m * 16 + li) * 32 + lg * 8);
#pragma unroll
    for (int n = 0; n < 2; ++n) {
      b1f[n] = *(const short8*)(B1s + (wc * 32 + n * 16 + li) * 32 + lg * 8);
      b3f[n] = *(const short8*)(B3s + (wc * 32 + n * 16 + li) * 32 + lg * 8);
    }
#pragma unroll
    for (int m = 0; m < 4; ++m)
#pragma unroll
      for (int n = 0; n < 2; ++n) {
        a1[m][n] = __builtin_amdgcn_mfma_f32_16x16x32_bf16(af[m], b1f[n], a1[m][n], 0, 0, 0);
        a3[m][n] = __builtin_amdgcn_mfma_f32_16x16x32_bf16(af[m], b3f[n], a3[m][n], 0, 0, 0);
      }
  }

#pragma unroll
  for (int m = 0; m < 4; ++m) {
    const int row = row0 + wr * 64 + m * 16 + lg * 4;
#pragma unroll
    for (int n = 0; n < 2; ++n) {
      const int col = col0 + wc * 32 + n * 16 + li;
#pragma unroll
      for (int r = 0; r < 4; ++r) {
        const float g1 = a1[m][n][r], g3 = a3[m][n][r];
        const float sl = g1 / (1.f + __expf(-g1));
        O[(size_t)(row + r) * N + col] = f2bf(sl * g3);
      }
    }
  }
}

// ---------- flash attention (causal), qkv:[4096][3072] bf16, out:[4096][1024] bf16 ----------
// 4 waves x 16 queries, KV tile 64. S^T = mfma(K, Q^T) -> per-lane stats for query li.
// O^T = mfma(V^T, P^T) -> alpha/linv lane-local, packed output stores.
// K: global_load_lds with pre-swizzled source; V: reg-transposed, swizzled b128 writes.
__global__ __launch_bounds__(256) void k_attn(const u16* __restrict__ qkv,
                                              u16* __restrict__ o) {
  const int LD = 3072;
  const int h = blockIdx.x & 15;
  const int qb = 63 - (blockIdx.x >> 4);  // heaviest q-blocks first
  const int q0 = qb * 64;
  const int tid = threadIdx.x, lane = tid & 63, w = tid >> 6;
  const int li = lane & 15, lg = lane >> 4;
  const int swzB = (li & 7) << 4;

  __shared__ __align__(16) u16 Ks[64 * 64];
  __shared__ __align__(16) u16 Vt[64 * 64];
  __shared__ __align__(16) u16 Ps[4 * 16 * 64];

  const int qrow = q0 + w * 16 + li;
  const u16* qp = qkv + (size_t)qrow * LD + h * 64;
  short8 qf0, qf1;
#pragma unroll
  for (int j = 0; j < 8; ++j) {
    qf0[j] = (short)(__builtin_bit_cast(u32, bf2f(qp[lg * 8 + j]) * 0.125f) >> 16);
    qf1[j] = (short)(__builtin_bit_cast(u32, bf2f(qp[32 + lg * 8 + j]) * 0.125f) >> 16);
  }

  const int krow = w * 16 + (lane >> 3);
  const int kcol = ((lane & 7) ^ (lane >> 3)) * 8;
  const u16* kg = qkv + 1024 + h * 64 + kcol;
  u16* klds0 = Ks + (w * 2 + 0) * 512 + lane * 8;
  u16* klds1 = Ks + (w * 2 + 1) * 512 + lane * 8;

  const int vd0 = (tid & 31) * 2;
  const int vkq = tid >> 5;
  const u16* vg = qkv + 2048 + h * 64 + vd0;
  u32* vl0 = (u32*)(Vt + (size_t)vd0 * 64 + (((vkq * 16) ^ ((vd0 & 7) << 4)) >> 1));
  u32* vl1 = (u32*)(Vt + (size_t)(vd0 + 1) * 64 + (((vkq * 16) ^ (((vd0 + 1) & 7) << 4)) >> 1));

  u16* pw = Ps + w * 1024 + li * 64;

  float msm = -1e30f, lsm = 0.f;
  f32x4 accO[4] = {};
  u32 vld[8];

  {
    const u16* vp = vg;
#pragma unroll
    for (int i = 0; i < 8; ++i) vld[i] = *(const u32*)(vp + (size_t)(vkq * 8 + i) * LD);
  }

  for (int k0 = 0; k0 <= q0; k0 += 64) {
    __syncthreads();
    GLD16(kg + (size_t)(k0 + krow) * LD, klds0);
    GLD16(kg + (size_t)(k0 + krow + 8) * LD, klds1);
    {
      u32 lo0 = (vld[0] & 0xffffu) | (vld[1] << 16);
      u32 lo1 = (vld[2] & 0xffffu) | (vld[3] << 16);
      u32 lo2 = (vld[4] & 0xffffu) | (vld[5] << 16);
      u32 lo3 = (vld[6] & 0xffffu) | (vld[7] << 16);
      u32 hi0 = (vld[0] >> 16) | (vld[1] & 0xffff0000u);
      u32 hi1 = (vld[2] >> 16) | (vld[3] & 0xffff0000u);
      u32 hi2 = (vld[4] >> 16) | (vld[5] & 0xffff0000u);
      u32 hi3 = (vld[6] >> 16) | (vld[7] & 0xffff0000u);
      *(uint4*)vl0 = make_uint4(lo0, lo1, lo2, lo3);
      *(uint4*)vl1 = make_uint4(hi0, hi1, hi2, hi3);
    }
    __syncthreads();
    if (k0 + 64 <= q0) {
      const u16* vp = vg + (size_t)(k0 + 64) * LD;
#pragma unroll
      for (int i = 0; i < 8; ++i) vld[i] = *(const u32*)(vp + (size_t)(vkq * 8 + i) * LD);
    }

    f32x4 st[4];
#pragma unroll
    for (int f = 0; f < 4; ++f) {
      const u16* kp = Ks + (size_t)(f * 16 + li) * 64;
      const short8 ka0 = *(const short8*)(kp + (((lg * 16) ^ swzB) >> 1));
      const short8 ka1 = *(const short8*)(kp + (((64 + lg * 16) ^ swzB) >> 1));
      f32x4 z = {};
      z = __builtin_amdgcn_mfma_f32_16x16x32_bf16(ka0, qf0, z, 0, 0, 0);
      st[f] = __builtin_amdgcn_mfma_f32_16x16x32_bf16(ka1, qf1, z, 0, 0, 0);
    }

    float sv[16];
    float mloc = -1e30f;
    if (k0 < q0) {
#pragma unroll
      for (int f = 0; f < 4; ++f)
#pragma unroll
        for (int r = 0; r < 4; ++r) {
          sv[f * 4 + r] = st[f][r];
          mloc = fmaxf(mloc, sv[f * 4 + r]);
        }
    } else {
#pragma unroll
      for (int f = 0; f < 4; ++f)
#pragma unroll
        for (int r = 0; r < 4; ++r) {
          const int kg2 = k0 + f * 16 + lg * 4 + r;
          sv[f * 4 + r] = (kg2 > qrow) ? -1e30f : st[f][r];
          mloc = fmaxf(mloc, sv[f * 4 + r]);
        }
    }
    mloc = fmaxf(mloc, __shfl_xor(mloc, 16));
    mloc = fmaxf(mloc, __shfl_xor(mloc, 32));
    const float mnew = fmaxf(msm, mloc);
    const float alpha = __expf(msm - mnew);
    float psum = 0.f;
#pragma unroll
    for (int f = 0; f < 4; ++f) {
      const float p0 = __expf(sv[f * 4 + 0] - mnew);
      const float p1 = __expf(sv[f * 4 + 1] - mnew);
      const float p2 = __expf(sv[f * 4 + 2] - mnew);
      const float p3 = __expf(sv[f * 4 + 3] - mnew);
      psum += (p0 + p1) + (p2 + p3);
      const u32 lo = (u32)f2bf(p0) | ((u32)f2bf(p1) << 16);
      const u32 hi = (u32)f2bf(p2) | ((u32)f2bf(p3) << 16);
      *(uint2*)(pw + (((f * 32 + lg * 8) ^ swzB) >> 1)) = make_uint2(lo, hi);
    }
    psum += __shfl_xor(psum, 16);
    psum += __shfl_xor(psum, 32);
    lsm = lsm * alpha + psum;
    msm = mnew;
#pragma unroll
    for (int n = 0; n < 4; ++n) {
      accO[n][0] *= alpha; accO[n][1] *= alpha;
      accO[n][2] *= alpha; accO[n][3] *= alpha;
    }

#pragma unroll
    for (int kk = 0; kk < 2; ++kk) {
      const int cofs = ((kk * 64 + lg * 16) ^ swzB) >> 1;
      const short8 pf = *(const short8*)(pw + cofs);
#pragma unroll
      for (int n = 0; n < 4; ++n) {
        const short8 vf = *(const short8*)(Vt + (size_t)(n * 16 + li) * 64 + cofs);
        accO[n] = __builtin_amdgcn_mfma_f32_16x16x32_bf16(vf, pf, accO[n], 0, 0, 0);
      }
    }
  }

  const float linv = 1.f / lsm;
  u16* op = o + (size_t)(q0 + w * 16 + li) * 1024 + h * 64;
#pragma unroll
  for (int n = 0; n < 4; ++n) {
    const u32 lo = (u32)f2bf(accO[n][0] * linv) | ((u32)f2bf(accO[n][1] * linv) << 16);
    const u32 hi = (u32)f2bf(accO[n][2] * linv) | ((u32)f2bf(accO[n][3] * linv) << 16);
    *(uint2*)(op + n * 16 + lg * 4) = make_uint2(lo, hi);
  }
}

extern "C" void kernel_launch(void* const* d_in, const int* in_sizes, int n_in,
                              void* d_out, int out_size, void* d_ws, size_t ws_size,
                              hipStream_t stream) {
  const float* x  = (const float*)d_in[0];
  const float* wq = (const float*)d_in[1];
  const float* wk = (const float*)d_in[2];
  const float* wv = (const float*)d_in[3];
  const float* wo = (const float*)d_in[4];
  const float* w1 = (const float*)d_in[5];
  const float* w2 = (const float*)d_in[6];   // w2 before w3 in dict order
  const float* w3 = (const float*)d_in[7];
  const float* ga = (const float*)d_in[8];
  const float* gf = (const float*)d_in[9];
  float* out = (float*)d_out;

  char* p = (char*)d_ws;
  auto take = [&](size_t n) { char* r = p; p += (n + 255) & ~(size_t)255; return r; };
  u16* wqkvo_t = (u16*)take(4096ull * 1024 * 1024 / 512 * 2);  // 4 x [1024][1024] bf16
  u16* w13_t   = (u16*)take(2ull * 2816 * 1024 * 2);           // w1^T then w3^T
  u16* w2_t    = (u16*)take(1024ull * 2816 * 2);
  u16* xn      = (u16*)take(4096ull * 1024 * 2);
  u16* qkvb    = (u16*)take(4096ull * 3072 * 2);
  u16* atn     = (u16*)take(4096ull * 1024 * 2);
  float* hb    = (float*)take(4096ull * 1024 * 4);
  u16* hn      = (u16*)take(4096ull * 1024 * 2);
  u16* ffb     = (u16*)take(4096ull * 2816 * 2);

  u16* wqkv_t = wqkvo_t;                       // first 3 x 1M
  u16* wo_t   = wqkvo_t + 3ull * 1024 * 1024;  // 4th
  u16* w1_t   = w13_t;
  u16* w3_t   = w13_t + 2816ull * 1024;

  k_tc4<<<dim3(32, 32, 4), 256, 0, stream>>>(wq, wk, wv, wo, wqkvo_t, 1024, 1024);
  k_tc4<<<dim3(88, 32, 2), 256, 0, stream>>>(w1, w3, w1, w3, w13_t, 1024, 2816);
  k_tc4<<<dim3(32, 88, 1), 256, 0, stream>>>(w2, w2, w2, w2, w2_t, 2816, 1024);

  k_rms<<<4096, 256, 0, stream>>>(x, ga, xn);
  k_gemm<0, 128><<<dim3(24, 32), 256, 0, stream>>>(xn, wqkv_t, qkvb, nullptr, nullptr, 4096, 3072, 1024);
  k_attn<<<1024, 256, 0, stream>>>(qkvb, atn);
  k_gemm<1, 64><<<dim3(16, 32), 256, 0, stream>>>(atn, wo_t, nullptr, hb, x, 4096, 1024, 1024);
  k_rms<<<4096, 256, 0, stream>>>(hb, gf, hn);
  k_ffn13<<<dim3(44, 32), 256, 0, stream>>>(hn, w1_t, w3_t, ffb, 4096, 2816, 1024);
  k_gemm<1, 64><<<dim3(16, 32), 256, 0, stream>>>(ffb, w2_t, nullptr, out, hb, 4096, 1024, 2816);
}

// Round 4
// 311.370 us; speedup vs baseline: 1.4129x; 1.0370x over previous
//
#include <hip/hip_runtime.h>
#include <stdint.h>

// TransformerBlock: x:[1,4096,1024] f32 -> out f32
// DIM=1024 NH=16 HD=64 HIDDEN=2816 SEQ=4096 eps=1e-5
// bf16 MFMA (16x16x32) GEMMs + flash attention (O^T form, swizzled LDS); fp32 residual path.

typedef unsigned short u16;
typedef unsigned int u32;
typedef __attribute__((ext_vector_type(8))) short short8;   // 8 x bf16 (4 VGPR)
typedef __attribute__((ext_vector_type(4))) float f32x4;

#define GLD16(G, L) __builtin_amdgcn_global_load_lds( \
    (__attribute__((address_space(1))) void*)(G),      \
    (__attribute__((address_space(3))) void*)(L), 16, 0, 0)

__device__ __forceinline__ u16 f2bf(float f) {  // RNE
  u32 u = __builtin_bit_cast(u32, f);
  u32 r = u + 0x7fffu + ((u >> 16) & 1u);
  return (u16)(r >> 16);
}
__device__ __forceinline__ float bf2f(u16 b) {
  u32 u = (u32)b << 16;
  return __builtin_bit_cast(float, u);
}
__device__ __forceinline__ u32 pk_bf16(float lo, float hi) {  // T12: no builtin on gfx950
  u32 r;
  asm("v_cvt_pk_bf16_f32 %0, %1, %2" : "=v"(r) : "v"(lo), "v"(hi));
  return r;
}

// ---------- transpose + convert: in[R][C] f32 -> out[C][R] bf16, z-muxed ----------
__global__ __launch_bounds__(256) void k_tc4(const float* __restrict__ s0,
                                             const float* __restrict__ s1,
                                             const float* __restrict__ s2,
                                             const float* __restrict__ s3,
                                             u16* __restrict__ out, int R, int C) {
  const int z = blockIdx.z;
  const float* in = (z == 0) ? s0 : (z == 1) ? s1 : (z == 2) ? s2 : s3;
  u16* o = out + (size_t)z * R * C;
  __shared__ float t[32][33];
  const int tx = threadIdx.x & 31, ty = threadIdx.x >> 5;
  const int c0 = blockIdx.x * 32, r0 = blockIdx.y * 32;
#pragma unroll
  for (int i = 0; i < 32; i += 8)
    t[ty + i][tx] = in[(size_t)(r0 + ty + i) * C + (c0 + tx)];
  __syncthreads();
#pragma unroll
  for (int i = 0; i < 32; i += 8)
    o[(size_t)(c0 + ty + i) * R + (r0 + tx)] = f2bf(t[tx][ty + i]);
}

// ---------- RMSNorm: f32 [4096][1024] -> bf16 ----------
__global__ __launch_bounds__(256) void k_rms(const float* __restrict__ x,
                                             const float* __restrict__ g,
                                             u16* __restrict__ o) {
  const int row = blockIdx.x, tid = threadIdx.x;
  const float4 v = ((const float4*)(x + (size_t)row * 1024))[tid];
  float ss = v.x * v.x + v.y * v.y + v.z * v.z + v.w * v.w;
#pragma unroll
  for (int ofs = 32; ofs > 0; ofs >>= 1) ss += __shfl_xor(ss, ofs);
  __shared__ float red[4];
  if ((tid & 63) == 0) red[tid >> 6] = ss;
  __syncthreads();
  const float s = rsqrtf((red[0] + red[1] + red[2] + red[3]) * (1.f / 1024.f) + 1e-5f);
  const float4 gv = ((const float4*)g)[tid];
  u32 lo = (u32)f2bf(v.x * s * gv.x) | ((u32)f2bf(v.y * s * gv.y) << 16);
  u32 hi = (u32)f2bf(v.z * s * gv.z) | ((u32)f2bf(v.w * s * gv.w) << 16);
  *(uint2*)(o + (size_t)row * 1024 + tid * 4) = make_uint2(lo, hi);
}

// ---------- GEMM: C[M,N] = A[M,K](bf16) @ Bt[N,K]^T(bf16), tile 128xTN ----------
// EPI 0: bf16 out.  EPI 1: f32 out = acc + resid.
template <int EPI, int TN>
__global__ __launch_bounds__(256) void k_gemm(const u16* __restrict__ A,
                                              const u16* __restrict__ Bt,
                                              u16* __restrict__ Obf,
                                              float* __restrict__ Of,
                                              const float* __restrict__ Rz,
                                              int M, int N, int K) {
  constexpr int NFR = TN / 32;             // n-frags per wave (waves 2x2)
  __shared__ __align__(16) u16 As[128 * 32];
  __shared__ __align__(16) u16 Bs[TN * 32];
  const int tid = threadIdx.x;
  const int lane = tid & 63, wave = tid >> 6;
  const int wr = wave >> 1, wc = wave & 1;
  const int li = lane & 15, lg = lane >> 4;
  const int row0 = blockIdx.y * 128, col0 = blockIdx.x * TN;

  f32x4 acc[4][NFR] = {};
  const int sr = tid >> 2, sc = (tid & 3) * 8;
  const u16* ag = A + (size_t)(row0 + sr) * K + sc;
  const u16* bg = Bt + (size_t)(col0 + sr) * K + sc;
  u16* al = As + tid * 8;
  u16* bl = Bs + tid * 8;
  const size_t rstep = (size_t)64 * K;

  for (int k0 = 0; k0 < K; k0 += 32) {
    __syncthreads();
    GLD16(ag + k0, al);
    GLD16(ag + rstep + k0, al + 2048);
    GLD16(bg + k0, bl);
    if constexpr (TN == 128) GLD16(bg + rstep + k0, bl + 2048);
    __syncthreads();
    short8 af[4], bfr[NFR];
#pragma unroll
    for (int m = 0; m < 4; ++m)
      af[m] = *(const short8*)(As + (wr * 64 + m * 16 + li) * 32 + lg * 8);
#pragma unroll
    for (int n = 0; n < NFR; ++n)
      bfr[n] = *(const short8*)(Bs + (wc * (TN / 2) + n * 16 + li) * 32 + lg * 8);
#pragma unroll
    for (int m = 0; m < 4; ++m)
#pragma unroll
      for (int n = 0; n < NFR; ++n)
        acc[m][n] = __builtin_amdgcn_mfma_f32_16x16x32_bf16(af[m], bfr[n], acc[m][n], 0, 0, 0);
  }

#pragma unroll
  for (int m = 0; m < 4; ++m) {
    const int row = row0 + wr * 64 + m * 16 + lg * 4;
#pragma unroll
    for (int n = 0; n < NFR; ++n) {
      const int col = col0 + wc * (TN / 2) + n * 16 + li;
#pragma unroll
      for (int r = 0; r < 4; ++r) {
        const size_t idx = (size_t)(row + r) * N + col;
        if (EPI == 0) Obf[idx] = f2bf(acc[m][n][r]);
        else          Of[idx] = acc[m][n][r] + Rz[idx];
      }
    }
  }
}

// ---------- fused SwiGLU FFN13: O = bf16( silu(A@B1^T) * (A@B3^T) ), tile 128x64 ----------
__global__ __launch_bounds__(256) void k_ffn13(const u16* __restrict__ A,
                                               const u16* __restrict__ B1,
                                               const u16* __restrict__ B3,
                                               u16* __restrict__ O,
                                               int M, int N, int K) {
  __shared__ __align__(16) u16 As[128 * 32];
  __shared__ __align__(16) u16 B1s[64 * 32];
  __shared__ __align__(16) u16 B3s[64 * 32];
  const int tid = threadIdx.x;
  const int lane = tid & 63, wave = tid >> 6;
  const int wr = wave >> 1, wc = wave & 1;
  const int li = lane & 15, lg = lane >> 4;
  const int row0 = blockIdx.y * 128, col0 = blockIdx.x * 64;

  f32x4 a1[4][2] = {}, a3[4][2] = {};
  const int sr = tid >> 2, sc = (tid & 3) * 8;
  const u16* ag = A + (size_t)(row0 + sr) * K + sc;
  const u16* b1g = B1 + (size_t)(col0 + sr) * K + sc;
  const u16* b3g = B3 + (size_t)(col0 + sr) * K + sc;
  u16* al = As + tid * 8;
  u16* b1l = B1s + tid * 8;
  u16* b3l = B3s + tid * 8;
  const size_t rstep = (size_t)64 * K;

  for (int k0 = 0; k0 < K; k0 += 32) {
    __syncthreads();
    GLD16(ag + k0, al);
    GLD16(ag + rstep + k0, al + 2048);
    GLD16(b1g + k0, b1l);
    GLD16(b3g + k0, b3l);
    __syncthreads();
    short8 af[4], b1f[2], b3f[2];
#pragma unroll
    for (int m = 0; m < 4; ++m)
      af[m] = *(const short8*)(As + (wr * 64 + m * 16 + li) * 32 + lg * 8);
#pragma unroll
    for (int n = 0; n < 2; ++n) {
      b1f[n] = *(const short8*)(B1s + (wc * 32 + n * 16 + li) * 32 + lg * 8);
      b3f[n] = *(const short8*)(B3s + (wc * 32 + n * 16 + li) * 32 + lg * 8);
    }
#pragma unroll
    for (int m = 0; m < 4; ++m)
#pragma unroll
      for (int n = 0; n < 2; ++n) {
        a1[m][n] = __builtin_amdgcn_mfma_f32_16x16x32_bf16(af[m], b1f[n], a1[m][n], 0, 0, 0);
        a3[m][n] = __builtin_amdgcn_mfma_f32_16x16x32_bf16(af[m], b3f[n], a3[m][n], 0, 0, 0);
      }
  }

#pragma unroll
  for (int m = 0; m < 4; ++m) {
    const int row = row0 + wr * 64 + m * 16 + lg * 4;
#pragma unroll
    for (int n = 0; n < 2; ++n) {
      const int col = col0 + wc * 32 + n * 16 + li;
#pragma unroll
      for (int r = 0; r < 4; ++r) {
        const float g1 = a1[m][n][r], g3 = a3[m][n][r];
        const float sl = g1 / (1.f + __expf(-g1));
        O[(size_t)(row + r) * N + col] = f2bf(sl * g3);
      }
    }
  }
}

// ---------- flash attention (causal), qkv:[4096][3072] bf16, out:[4096][1024] bf16 ----------
// 8 waves x 16 queries (QBLK=128), KV tile 64. S^T = mfma(K, Q^T) -> stats lane-local (query=li).
// O^T = mfma(V^T, P^T). exp2-domain softmax (log2e folded into Q scale), defer-max (T13, THR=8),
// v_cvt_pk_bf16_f32 packing (T12). K via global_load_lds w/ pre-swizzled source; V reg-transposed.
__global__ __launch_bounds__(512) void k_attn(const u16* __restrict__ qkv,
                                              u16* __restrict__ o) {
  const int LD = 3072;
  const int h = blockIdx.x & 15;
  const int qb = 31 - (blockIdx.x >> 4);  // heaviest q-blocks first
  const int q0 = qb * 128;
  const int tid = threadIdx.x, lane = tid & 63, w = tid >> 6;
  const int li = lane & 15, lg = lane >> 4;
  const int swzB = (li & 7) << 4;

  __shared__ __align__(16) u16 Ks[64 * 64];       // [key][d], swizzled
  __shared__ __align__(16) u16 Vt[64 * 64];       // [d][key], swizzled
  __shared__ __align__(16) u16 Ps[8 * 16 * 64];   // per-wave [q][key], swizzled

  // Q fragment, pre-scaled by (1/sqrt(64)) * log2(e)  -> scores in log2 units
  const int qrow = q0 + w * 16 + li;
  const u16* qp = qkv + (size_t)qrow * LD + h * 64;
  const float QS = 0.125f * 1.44269504f;
  short8 qf0, qf1;
#pragma unroll
  for (int j = 0; j < 8; ++j) {
    qf0[j] = (short)f2bf(bf2f(qp[lg * 8 + j]) * QS);
    qf1[j] = (short)f2bf(bf2f(qp[32 + lg * 8 + j]) * QS);
  }

  // K staging: 1 global_load_lds per thread (512 x 16B = 64x64 bf16 tile)
  const int krow = tid >> 3;
  const u16* kg = qkv + 1024 + h * 64 + ((tid & 7) ^ (krow & 7)) * 8;
  u16* klds = Ks + tid * 8;

  // V staging: 4 u32 column loads -> 2 swizzled uint2 writes
  const int vd0 = (tid & 31) * 2;
  const int vkq = tid >> 5;                              // 0..15, 4 keys each
  const u16* vg = qkv + 2048 + h * 64 + vd0;
  u16* vl0 = Vt + (size_t)vd0 * 64 + (((vkq * 8) ^ ((vd0 & 7) << 4)) >> 1);
  u16* vl1 = Vt + (size_t)(vd0 + 1) * 64 + (((vkq * 8) ^ (((vd0 + 1) & 7) << 4)) >> 1);

  u16* pw = Ps + w * 1024 + li * 64;

  float msm = -1e30f, lsm = 0.f;
  f32x4 accO[4] = {};
  u32 vld[4];

  {  // prologue: V loads for tile 0
#pragma unroll
    for (int i = 0; i < 4; ++i) vld[i] = *(const u32*)(vg + (size_t)(vkq * 4 + i) * LD);
  }

  const int kend = q0 + 64;        // last tile start (covers queries q0..q0+127)
  const int wqmax = q0 + w * 16 + 15;
  for (int k0 = 0; k0 <= kend; k0 += 64) {
    __syncthreads();
    GLD16(kg + (size_t)(k0 + krow) * LD, klds);
    {  // V pack + swizzled write
      u32 lo0 = (vld[0] & 0xffffu) | (vld[1] << 16);
      u32 lo1 = (vld[2] & 0xffffu) | (vld[3] << 16);
      u32 hi0 = (vld[0] >> 16) | (vld[1] & 0xffff0000u);
      u32 hi1 = (vld[2] >> 16) | (vld[3] & 0xffff0000u);
      *(uint2*)vl0 = make_uint2(lo0, lo1);
      *(uint2*)vl1 = make_uint2(hi0, hi1);
    }
    __syncthreads();
    if (k0 + 64 <= kend) {  // prefetch next tile's V (in flight during compute)
      const u16* vp = vg + (size_t)(k0 + 64) * LD;
#pragma unroll
      for (int i = 0; i < 4; ++i) vld[i] = *(const u32*)(vp + (size_t)(vkq * 4 + i) * LD);
    }

    if (k0 <= wqmax) {  // wave-uniform
      // ---- QK^T: S^T[key][q] ----
      f32x4 st[4];
#pragma unroll
      for (int f = 0; f < 4; ++f) {
        const u16* kp = Ks + (size_t)(f * 16 + li) * 64;
        const short8 ka0 = *(const short8*)(kp + (((lg * 16) ^ swzB) >> 1));
        const short8 ka1 = *(const short8*)(kp + (((64 + lg * 16) ^ swzB) >> 1));
        f32x4 z = {};
        z = __builtin_amdgcn_mfma_f32_16x16x32_bf16(ka0, qf0, z, 0, 0, 0);
        st[f] = __builtin_amdgcn_mfma_f32_16x16x32_bf16(ka1, qf1, z, 0, 0, 0);
      }

      // ---- online softmax in log2 domain, stats lane-local (query = li) ----
      float sv[16];
      float mloc = -1e30f;
      if (k0 + 63 <= q0 + w * 16) {  // fully unmasked tile for this wave
#pragma unroll
        for (int f = 0; f < 4; ++f)
#pragma unroll
          for (int r = 0; r < 4; ++r) {
            sv[f * 4 + r] = st[f][r];
            mloc = fmaxf(mloc, sv[f * 4 + r]);
          }
      } else {                       // diagonal tile
#pragma unroll
        for (int f = 0; f < 4; ++f)
#pragma unroll
          for (int r = 0; r < 4; ++r) {
            const int kg2 = k0 + f * 16 + lg * 4 + r;
            sv[f * 4 + r] = (kg2 > qrow) ? -1e30f : st[f][r];
            mloc = fmaxf(mloc, sv[f * 4 + r]);
          }
      }
      mloc = fmaxf(mloc, __shfl_xor(mloc, 16));
      mloc = fmaxf(mloc, __shfl_xor(mloc, 32));
      if (!__all(mloc - msm <= 8.0f)) {   // T13 defer-max: rescale only on real growth
        const float mnew = fmaxf(msm, mloc);
        const float alpha = __builtin_amdgcn_exp2f(msm - mnew);
        lsm *= alpha;
#pragma unroll
        for (int n = 0; n < 4; ++n) {
          accO[n][0] *= alpha; accO[n][1] *= alpha;
          accO[n][2] *= alpha; accO[n][3] *= alpha;
        }
        msm = mnew;
      }
      float psum = 0.f;
#pragma unroll
      for (int f = 0; f < 4; ++f) {
        const float p0 = __builtin_amdgcn_exp2f(sv[f * 4 + 0] - msm);
        const float p1 = __builtin_amdgcn_exp2f(sv[f * 4 + 1] - msm);
        const float p2 = __builtin_amdgcn_exp2f(sv[f * 4 + 2] - msm);
        const float p3 = __builtin_amdgcn_exp2f(sv[f * 4 + 3] - msm);
        psum += (p0 + p1) + (p2 + p3);
        *(uint2*)(pw + (((f * 32 + lg * 8) ^ swzB) >> 1)) =
            make_uint2(pk_bf16(p0, p1), pk_bf16(p2, p3));
      }
      psum += __shfl_xor(psum, 16);
      psum += __shfl_xor(psum, 32);
      lsm += psum;

      // ---- PV: O^T[d][q] += V^T @ P^T ----
#pragma unroll
      for (int kk = 0; kk < 2; ++kk) {
        const int cofs = ((kk * 64 + lg * 16) ^ swzB) >> 1;
        const short8 pf = *(const short8*)(pw + cofs);
#pragma unroll
        for (int n = 0; n < 4; ++n) {
          const short8 vf = *(const short8*)(Vt + (size_t)(n * 16 + li) * 64 + cofs);
          accO[n] = __builtin_amdgcn_mfma_f32_16x16x32_bf16(vf, pf, accO[n], 0, 0, 0);
        }
      }
    }
  }

  // ---- epilogue: O^T -> o[q][h*64+d], packed 8B stores ----
  const float linv = 1.f / lsm;
  u16* op = o + (size_t)qrow * 1024 + h * 64;
#pragma unroll
  for (int n = 0; n < 4; ++n) {
    *(uint2*)(op + n * 16 + lg * 4) =
        make_uint2(pk_bf16(accO[n][0] * linv, accO[n][1] * linv),
                   pk_bf16(accO[n][2] * linv, accO[n][3] * linv));
  }
}

extern "C" void kernel_launch(void* const* d_in, const int* in_sizes, int n_in,
                              void* d_out, int out_size, void* d_ws, size_t ws_size,
                              hipStream_t stream) {
  const float* x  = (const float*)d_in[0];
  const float* wq = (const float*)d_in[1];
  const float* wk = (const float*)d_in[2];
  const float* wv = (const float*)d_in[3];
  const float* wo = (const float*)d_in[4];
  const float* w1 = (const float*)d_in[5];
  const float* w2 = (const float*)d_in[6];   // w2 before w3 in dict order
  const float* w3 = (const float*)d_in[7];
  const float* ga = (const float*)d_in[8];
  const float* gf = (const float*)d_in[9];
  float* out = (float*)d_out;

  char* p = (char*)d_ws;
  auto take = [&](size_t n) { char* r = p; p += (n + 255) & ~(size_t)255; return r; };
  u16* wqkvo_t = (u16*)take(4ull * 1024 * 1024 * 2);   // 4 x [1024][1024] bf16
  u16* w13_t   = (u16*)take(2ull * 2816 * 1024 * 2);   // w1^T then w3^T
  u16* w2_t    = (u16*)take(1024ull * 2816 * 2);
  u16* xn      = (u16*)take(4096ull * 1024 * 2);
  u16* qkvb    = (u16*)take(4096ull * 3072 * 2);
  u16* atn     = (u16*)take(4096ull * 1024 * 2);
  float* hb    = (float*)take(4096ull * 1024 * 4);
  u16* hn      = (u16*)take(4096ull * 1024 * 2);
  u16* ffb     = (u16*)take(4096ull * 2816 * 2);

  u16* wqkv_t = wqkvo_t;
  u16* wo_t   = wqkvo_t + 3ull * 1024 * 1024;
  u16* w1_t   = w13_t;
  u16* w3_t   = w13_t + 2816ull * 1024;

  k_tc4<<<dim3(32, 32, 4), 256, 0, stream>>>(wq, wk, wv, wo, wqkvo_t, 1024, 1024);
  k_tc4<<<dim3(88, 32, 2), 256, 0, stream>>>(w1, w3, w1, w3, w13_t, 1024, 2816);
  k_tc4<<<dim3(32, 88, 1), 256, 0, stream>>>(w2, w2, w2, w2, w2_t, 2816, 1024);

  k_rms<<<4096, 256, 0, stream>>>(x, ga, xn);
  k_gemm<0, 128><<<dim3(24, 32), 256, 0, stream>>>(xn, wqkv_t, qkvb, nullptr, nullptr, 4096, 3072, 1024);
  k_attn<<<512, 512, 0, stream>>>(qkvb, atn);
  k_gemm<1, 64><<<dim3(16, 32), 256, 0, stream>>>(atn, wo_t, nullptr, hb, x, 4096, 1024, 1024);
  k_rms<<<4096, 256, 0, stream>>>(hb, gf, hn);
  k_ffn13<<<dim3(44, 32), 256, 0, stream>>>(hn, w1_t, w3_t, ffb, 4096, 2816, 1024);
  k_gemm<1, 64><<<dim3(16, 32), 256, 0, stream>>>(ffb, w2_t, nullptr, out, hb, 4096, 1024, 2816);
}

// Round 5
// 297.715 us; speedup vs baseline: 1.4777x; 1.0459x over previous
//
#include <hip/hip_runtime.h>
#include <stdint.h>

// TransformerBlock: x:[1,4096,1024] f32 -> out f32
// DIM=1024 NH=16 HD=64 HIDDEN=2816 SEQ=4096 eps=1e-5
// bf16 MFMA (16x16x32) GEMMs + flash attention (flash-decoding split, O^T form); fp32 residuals.

typedef unsigned short u16;
typedef unsigned int u32;
typedef __attribute__((ext_vector_type(8))) short short8;   // 8 x bf16 (4 VGPR)
typedef __attribute__((ext_vector_type(4))) float f32x4;

#define GLD16(G, L) __builtin_amdgcn_global_load_lds( \
    (__attribute__((address_space(1))) void*)(G),      \
    (__attribute__((address_space(3))) void*)(L), 16, 0, 0)

__device__ __forceinline__ u16 f2bf(float f) {  // RNE
  u32 u = __builtin_bit_cast(u32, f);
  u32 r = u + 0x7fffu + ((u >> 16) & 1u);
  return (u16)(r >> 16);
}
__device__ __forceinline__ float bf2f(u16 b) {
  u32 u = (u32)b << 16;
  return __builtin_bit_cast(float, u);
}
__device__ __forceinline__ u32 pk_bf16(float lo, float hi) {  // T12
  u32 r;
  asm("v_cvt_pk_bf16_f32 %0, %1, %2" : "=v"(r) : "v"(lo), "v"(hi));
  return r;
}

// ---------- transpose + convert: in[R][C] f32 -> out[C][R] bf16, z-muxed ----------
__global__ __launch_bounds__(256) void k_tc4(const float* __restrict__ s0,
                                             const float* __restrict__ s1,
                                             const float* __restrict__ s2,
                                             const float* __restrict__ s3,
                                             u16* __restrict__ out, int R, int C) {
  const int z = blockIdx.z;
  const float* in = (z == 0) ? s0 : (z == 1) ? s1 : (z == 2) ? s2 : s3;
  u16* o = out + (size_t)z * R * C;
  __shared__ float t[32][33];
  const int tx = threadIdx.x & 31, ty = threadIdx.x >> 5;
  const int c0 = blockIdx.x * 32, r0 = blockIdx.y * 32;
#pragma unroll
  for (int i = 0; i < 32; i += 8)
    t[ty + i][tx] = in[(size_t)(r0 + ty + i) * C + (c0 + tx)];
  __syncthreads();
#pragma unroll
  for (int i = 0; i < 32; i += 8)
    o[(size_t)(c0 + ty + i) * R + (r0 + tx)] = f2bf(t[tx][ty + i]);
}

// ---------- RMSNorm: f32 [4096][1024] -> bf16 ----------
__global__ __launch_bounds__(256) void k_rms(const float* __restrict__ x,
                                             const float* __restrict__ g,
                                             u16* __restrict__ o) {
  const int row = blockIdx.x, tid = threadIdx.x;
  const float4 v = ((const float4*)(x + (size_t)row * 1024))[tid];
  float ss = v.x * v.x + v.y * v.y + v.z * v.z + v.w * v.w;
#pragma unroll
  for (int ofs = 32; ofs > 0; ofs >>= 1) ss += __shfl_xor(ss, ofs);
  __shared__ float red[4];
  if ((tid & 63) == 0) red[tid >> 6] = ss;
  __syncthreads();
  const float s = rsqrtf((red[0] + red[1] + red[2] + red[3]) * (1.f / 1024.f) + 1e-5f);
  const float4 gv = ((const float4*)g)[tid];
  u32 lo = (u32)f2bf(v.x * s * gv.x) | ((u32)f2bf(v.y * s * gv.y) << 16);
  u32 hi = (u32)f2bf(v.z * s * gv.z) | ((u32)f2bf(v.w * s * gv.w) << 16);
  *(uint2*)(o + (size_t)row * 1024 + tid * 4) = make_uint2(lo, hi);
}

// ---------- GEMM: C[M,N] = A[M,K](bf16) @ Bt[N,K]^T(bf16), tile 128xTN ----------
// EPI 0: bf16 out.  EPI 1: f32 out = acc + resid.
template <int EPI, int TN>
__global__ __launch_bounds__(256) void k_gemm(const u16* __restrict__ A,
                                              const u16* __restrict__ Bt,
                                              u16* __restrict__ Obf,
                                              float* __restrict__ Of,
                                              const float* __restrict__ Rz,
                                              int M, int N, int K) {
  constexpr int NFR = TN / 32;             // n-frags per wave (waves 2x2)
  __shared__ __align__(16) u16 As[128 * 32];
  __shared__ __align__(16) u16 Bs[TN * 32];
  const int tid = threadIdx.x;
  const int lane = tid & 63, wave = tid >> 6;
  const int wr = wave >> 1, wc = wave & 1;
  const int li = lane & 15, lg = lane >> 4;
  const int row0 = blockIdx.y * 128, col0 = blockIdx.x * TN;

  f32x4 acc[4][NFR] = {};
  const int sr = tid >> 2, sc = (tid & 3) * 8;
  const u16* ag = A + (size_t)(row0 + sr) * K + sc;
  const u16* bg = Bt + (size_t)(col0 + sr) * K + sc;
  u16* al = As + tid * 8;
  u16* bl = Bs + tid * 8;
  const size_t rstep = (size_t)64 * K;

  for (int k0 = 0; k0 < K; k0 += 32) {
    __syncthreads();
    GLD16(ag + k0, al);
    GLD16(ag + rstep + k0, al + 2048);
    GLD16(bg + k0, bl);
    if constexpr (TN == 128) GLD16(bg + rstep + k0, bl + 2048);
    __syncthreads();
    short8 af[4], bfr[NFR];
#pragma unroll
    for (int m = 0; m < 4; ++m)
      af[m] = *(const short8*)(As + (wr * 64 + m * 16 + li) * 32 + lg * 8);
#pragma unroll
    for (int n = 0; n < NFR; ++n)
      bfr[n] = *(const short8*)(Bs + (wc * (TN / 2) + n * 16 + li) * 32 + lg * 8);
#pragma unroll
    for (int m = 0; m < 4; ++m)
#pragma unroll
      for (int n = 0; n < NFR; ++n)
        acc[m][n] = __builtin_amdgcn_mfma_f32_16x16x32_bf16(af[m], bfr[n], acc[m][n], 0, 0, 0);
  }

#pragma unroll
  for (int m = 0; m < 4; ++m) {
    const int row = row0 + wr * 64 + m * 16 + lg * 4;
#pragma unroll
    for (int n = 0; n < NFR; ++n) {
      const int col = col0 + wc * (TN / 2) + n * 16 + li;
#pragma unroll
      for (int r = 0; r < 4; ++r) {
        const size_t idx = (size_t)(row + r) * N + col;
        if (EPI == 0) Obf[idx] = f2bf(acc[m][n][r]);
        else          Of[idx] = acc[m][n][r] + Rz[idx];
      }
    }
  }
}

// ---------- fused SwiGLU FFN13: O = bf16( silu(A@B1^T) * (A@B3^T) ), tile 128x64 ----------
__global__ __launch_bounds__(256) void k_ffn13(const u16* __restrict__ A,
                                               const u16* __restrict__ B1,
                                               const u16* __restrict__ B3,
                                               u16* __restrict__ O,
                                               int M, int N, int K) {
  __shared__ __align__(16) u16 As[128 * 32];
  __shared__ __align__(16) u16 B1s[64 * 32];
  __shared__ __align__(16) u16 B3s[64 * 32];
  const int tid = threadIdx.x;
  const int lane = tid & 63, wave = tid >> 6;
  const int wr = wave >> 1, wc = wave & 1;
  const int li = lane & 15, lg = lane >> 4;
  const int row0 = blockIdx.y * 128, col0 = blockIdx.x * 64;

  f32x4 a1[4][2] = {}, a3[4][2] = {};
  const int sr = tid >> 2, sc = (tid & 3) * 8;
  const u16* ag = A + (size_t)(row0 + sr) * K + sc;
  const u16* b1g = B1 + (size_t)(col0 + sr) * K + sc;
  const u16* b3g = B3 + (size_t)(col0 + sr) * K + sc;
  u16* al = As + tid * 8;
  u16* b1l = B1s + tid * 8;
  u16* b3l = B3s + tid * 8;
  const size_t rstep = (size_t)64 * K;

  for (int k0 = 0; k0 < K; k0 += 32) {
    __syncthreads();
    GLD16(ag + k0, al);
    GLD16(ag + rstep + k0, al + 2048);
    GLD16(b1g + k0, b1l);
    GLD16(b3g + k0, b3l);
    __syncthreads();
    short8 af[4], b1f[2], b3f[2];
#pragma unroll
    for (int m = 0; m < 4; ++m)
      af[m] = *(const short8*)(As + (wr * 64 + m * 16 + li) * 32 + lg * 8);
#pragma unroll
    for (int n = 0; n < 2; ++n) {
      b1f[n] = *(const short8*)(B1s + (wc * 32 + n * 16 + li) * 32 + lg * 8);
      b3f[n] = *(const short8*)(B3s + (wc * 32 + n * 16 + li) * 32 + lg * 8);
    }
#pragma unroll
    for (int m = 0; m < 4; ++m)
#pragma unroll
      for (int n = 0; n < 2; ++n) {
        a1[m][n] = __builtin_amdgcn_mfma_f32_16x16x32_bf16(af[m], b1f[n], a1[m][n], 0, 0, 0);
        a3[m][n] = __builtin_amdgcn_mfma_f32_16x16x32_bf16(af[m], b3f[n], a3[m][n], 0, 0, 0);
      }
  }

#pragma unroll
  for (int m = 0; m < 4; ++m) {
    const int row = row0 + wr * 64 + m * 16 + lg * 4;
#pragma unroll
    for (int n = 0; n < 2; ++n) {
      const int col = col0 + wc * 32 + n * 16 + li;
#pragma unroll
      for (int r = 0; r < 4; ++r) {
        const float g1 = a1[m][n][r], g3 = a3[m][n][r];
        const float sl = g1 / (1.f + __expf(-g1));
        O[(size_t)(row + r) * N + col] = f2bf(sl * g3);
      }
    }
  }
}

// ---------- flash attention pass 1 (causal, flash-decoding split + pairing) ----------
// Work item = (h, qb, kv-half j); both halves of qb have exactly qb+1 tiles of 64 keys.
// Block = pair {qb=p, qb=31-p} at same (h, j) -> uniform 33 tiles per block, 512 blocks.
// 8 waves x 16 queries (QBLK=128). S^T = mfma(K, Q^T), stats lane-local (query = li).
// O^T = mfma(V^T, P^T). exp2-domain softmax, defer-max, cvt_pk packing.
// Partials: Opart[item][q 128][d 64] f32, ml[item][{m,l}][q 128] f32, item=(h*32+qb)*2+j.
__global__ __launch_bounds__(512) void k_attn(const u16* __restrict__ qkv,
                                              float* __restrict__ Opart,
                                              float* __restrict__ ml) {
  const int LD = 3072;
  const int b = blockIdx.x;
  const int h = b & 15;
  const int p = (b >> 4) >> 1;
  const int j = (b >> 4) & 1;
  const int tid = threadIdx.x, lane = tid & 63, w = tid >> 6;
  const int li = lane & 15, lg = lane >> 4;
  const int swzB = (li & 7) << 4;
  const float QS = 0.125f * 1.44269504f;

  __shared__ __align__(16) u16 Ks[64 * 64];       // [key][d], swizzled
  __shared__ __align__(16) u16 Vt[64 * 64];       // [d][key], swizzled
  __shared__ __align__(16) u16 Ps[8 * 16 * 64];   // per-wave [q][key], swizzled

  const int krow = tid >> 3;
  const u16* kg = qkv + 1024 + h * 64 + ((tid & 7) ^ (krow & 7)) * 8;
  u16* klds = Ks + tid * 8;

  const int vd0 = (tid & 31) * 2;
  const int vkq = tid >> 5;                       // 0..15, 4 keys each
  const u16* vg = qkv + 2048 + h * 64 + vd0;
  u16* vl0 = Vt + (size_t)vd0 * 64 + (((vkq * 8) ^ ((vd0 & 7) << 4)) >> 1);
  u16* vl1 = Vt + (size_t)(vd0 + 1) * 64 + (((vkq * 8) ^ (((vd0 + 1) & 7) << 4)) >> 1);
  u16* pw = Ps + w * 1024 + li * 64;

  for (int sub = 0; sub < 2; ++sub) {
    const int qb = sub ? (31 - p) : p;
    const int q0 = qb * 128;
    const int t0 = j ? (qb + 1) : 0;
    const int t1 = j ? (2 * qb + 2) : (qb + 1);
    const int qrow = q0 + w * 16 + li;
    const int wqmax = q0 + w * 16 + 15;

    const u16* qp = qkv + (size_t)qrow * LD + h * 64;
    short8 qf0, qf1;
#pragma unroll
    for (int jj = 0; jj < 8; ++jj) {
      qf0[jj] = (short)f2bf(bf2f(qp[lg * 8 + jj]) * QS);
      qf1[jj] = (short)f2bf(bf2f(qp[32 + lg * 8 + jj]) * QS);
    }

    float msm = -1e30f, lsm = 0.f;
    f32x4 accO[4] = {};
    u32 vld[4];
#pragma unroll
    for (int i = 0; i < 4; ++i)
      vld[i] = *(const u32*)(vg + (size_t)(t0 * 64 + vkq * 4 + i) * LD);

    for (int t = t0; t < t1; ++t) {
      const int k0 = t * 64;
      __syncthreads();
      GLD16(kg + (size_t)(k0 + krow) * LD, klds);
      {  // V pack + swizzled write
        u32 lo0 = (vld[0] & 0xffffu) | (vld[1] << 16);
        u32 lo1 = (vld[2] & 0xffffu) | (vld[3] << 16);
        u32 hi0 = (vld[0] >> 16) | (vld[1] & 0xffff0000u);
        u32 hi1 = (vld[2] >> 16) | (vld[3] & 0xffff0000u);
        *(uint2*)vl0 = make_uint2(lo0, lo1);
        *(uint2*)vl1 = make_uint2(hi0, hi1);
      }
      __syncthreads();
      if (t + 1 < t1) {  // prefetch next tile's V
        const u16* vp = vg + (size_t)(t + 1) * 64 * LD;
#pragma unroll
        for (int i = 0; i < 4; ++i) vld[i] = *(const u32*)(vp + (size_t)(vkq * 4 + i) * LD);
      }

      if (k0 <= wqmax) {  // wave-uniform
        // ---- QK^T: S^T[key][q] ----
        f32x4 st[4];
#pragma unroll
        for (int f = 0; f < 4; ++f) {
          const u16* kp = Ks + (size_t)(f * 16 + li) * 64;
          const short8 ka0 = *(const short8*)(kp + (((lg * 16) ^ swzB) >> 1));
          const short8 ka1 = *(const short8*)(kp + (((64 + lg * 16) ^ swzB) >> 1));
          f32x4 z = {};
          z = __builtin_amdgcn_mfma_f32_16x16x32_bf16(ka0, qf0, z, 0, 0, 0);
          st[f] = __builtin_amdgcn_mfma_f32_16x16x32_bf16(ka1, qf1, z, 0, 0, 0);
        }

        // ---- online softmax (log2 domain), stats lane-local (query = li) ----
        float sv[16];
        float mloc = -1e30f;
        if (k0 + 63 <= q0 + w * 16) {  // fully unmasked for this wave
#pragma unroll
          for (int f = 0; f < 4; ++f)
#pragma unroll
            for (int r = 0; r < 4; ++r) {
              sv[f * 4 + r] = st[f][r];
              mloc = fmaxf(mloc, sv[f * 4 + r]);
            }
        } else {                       // diagonal tile
#pragma unroll
          for (int f = 0; f < 4; ++f)
#pragma unroll
            for (int r = 0; r < 4; ++r) {
              const int kg2 = k0 + f * 16 + lg * 4 + r;
              sv[f * 4 + r] = (kg2 > qrow) ? -1e30f : st[f][r];
              mloc = fmaxf(mloc, sv[f * 4 + r]);
            }
        }
        mloc = fmaxf(mloc, __shfl_xor(mloc, 16));
        mloc = fmaxf(mloc, __shfl_xor(mloc, 32));
        if (!__all(mloc - msm <= 8.0f)) {   // T13 defer-max
          const float mnew = fmaxf(msm, mloc);
          const float alpha = __builtin_amdgcn_exp2f(msm - mnew);
          lsm *= alpha;
#pragma unroll
          for (int n = 0; n < 4; ++n) {
            accO[n][0] *= alpha; accO[n][1] *= alpha;
            accO[n][2] *= alpha; accO[n][3] *= alpha;
          }
          msm = mnew;
        }
        float psum = 0.f;
#pragma unroll
        for (int f = 0; f < 4; ++f) {
          const float p0 = __builtin_amdgcn_exp2f(sv[f * 4 + 0] - msm);
          const float p1 = __builtin_amdgcn_exp2f(sv[f * 4 + 1] - msm);
          const float p2 = __builtin_amdgcn_exp2f(sv[f * 4 + 2] - msm);
          const float p3 = __builtin_amdgcn_exp2f(sv[f * 4 + 3] - msm);
          psum += (p0 + p1) + (p2 + p3);
          *(uint2*)(pw + (((f * 32 + lg * 8) ^ swzB) >> 1)) =
              make_uint2(pk_bf16(p0, p1), pk_bf16(p2, p3));
        }
        psum += __shfl_xor(psum, 16);
        psum += __shfl_xor(psum, 32);
        lsm += psum;

        // ---- PV: O^T[d][q] += V^T @ P^T ----
#pragma unroll
        for (int kk = 0; kk < 2; ++kk) {
          const int cofs = ((kk * 64 + lg * 16) ^ swzB) >> 1;
          const short8 pf = *(const short8*)(pw + cofs);
#pragma unroll
          for (int n = 0; n < 4; ++n) {
            const short8 vf = *(const short8*)(Vt + (size_t)(n * 16 + li) * 64 + cofs);
            accO[n] = __builtin_amdgcn_mfma_f32_16x16x32_bf16(vf, pf, accO[n], 0, 0, 0);
          }
        }
      }
    }

    // ---- store partials ----
    const int item = (h * 32 + qb) * 2 + j;
    float* op = Opart + (size_t)item * 8192 + (w * 16 + li) * 64 + lg * 4;
#pragma unroll
    for (int n = 0; n < 4; ++n)
      *(f32x4*)(op + n * 16) = accO[n];
    if (lg == 0) {
      ml[item * 256 + w * 16 + li] = msm;
      ml[item * 256 + 128 + w * 16 + li] = lsm;
    }
  }
}

// ---------- flash attention pass 2: merge the two kv-halves ----------
__global__ __launch_bounds__(256) void k_amerge(const float* __restrict__ Opart,
                                                const float* __restrict__ ml,
                                                u16* __restrict__ o) {
  const int b = blockIdx.x;             // 512 = 16 h x 32 qb
  const int h = b & 15, qb = b >> 4;
  const int q = threadIdx.x >> 1;
  const int dh = (threadIdx.x & 1) * 32;
  const int i0 = (h * 32 + qb) * 2;
  const float m0 = ml[i0 * 256 + q], l0 = ml[i0 * 256 + 128 + q];
  const float m1 = ml[(i0 + 1) * 256 + q], l1 = ml[(i0 + 1) * 256 + 128 + q];
  const float M = fmaxf(m0, m1);
  const float s0 = __builtin_amdgcn_exp2f(m0 - M);
  const float s1 = __builtin_amdgcn_exp2f(m1 - M);
  const float L = s0 * l0 + s1 * l1;
  const float r0 = s0 / L, r1 = s1 / L;
  const float* p0 = Opart + (size_t)i0 * 8192 + q * 64 + dh;
  const float* p1 = p0 + 8192;
  u16* op = o + (size_t)(qb * 128 + q) * 1024 + h * 64 + dh;
#pragma unroll
  for (int dd = 0; dd < 32; dd += 4) {
    const f32x4 a = *(const f32x4*)(p0 + dd);
    const f32x4 c = *(const f32x4*)(p1 + dd);
    *(uint2*)(op + dd) =
        make_uint2(pk_bf16(a[0] * r0 + c[0] * r1, a[1] * r0 + c[1] * r1),
                   pk_bf16(a[2] * r0 + c[2] * r1, a[3] * r0 + c[3] * r1));
  }
}

extern "C" void kernel_launch(void* const* d_in, const int* in_sizes, int n_in,
                              void* d_out, int out_size, void* d_ws, size_t ws_size,
                              hipStream_t stream) {
  const float* x  = (const float*)d_in[0];
  const float* wq = (const float*)d_in[1];
  const float* wk = (const float*)d_in[2];
  const float* wv = (const float*)d_in[3];
  const float* wo = (const float*)d_in[4];
  const float* w1 = (const float*)d_in[5];
  const float* w2 = (const float*)d_in[6];   // w2 before w3 in dict order
  const float* w3 = (const float*)d_in[7];
  const float* ga = (const float*)d_in[8];
  const float* gf = (const float*)d_in[9];
  float* out = (float*)d_out;

  char* p = (char*)d_ws;
  auto take = [&](size_t n) { char* r = p; p += (n + 255) & ~(size_t)255; return r; };
  u16* wqkvo_t = (u16*)take(4ull * 1024 * 1024 * 2);   // 4 x [1024][1024] bf16
  u16* w13_t   = (u16*)take(2ull * 2816 * 1024 * 2);   // w1^T then w3^T
  u16* w2_t    = (u16*)take(1024ull * 2816 * 2);
  u16* xn      = (u16*)take(4096ull * 1024 * 2);
  u16* qkvb    = (u16*)take(4096ull * 3072 * 2);
  u16* atn     = (u16*)take(4096ull * 1024 * 2);
  // union region: {Opart 33.6MB + ml 1MB} (attn passes)  vs  {hb, hn, ffb} (post-attn)
  char* uni    = take(48234496);
  float* Opart = (float*)uni;                          // 1024 items x 8192 f32
  float* mlb   = (float*)(uni + 1024ull * 8192 * 4);   // 1024 items x 256 f32
  float* hb    = (float*)uni;                          // 4096x1024 f32
  u16* hn      = (u16*)(uni + 4096ull * 1024 * 4);     // 4096x1024 bf16
  u16* ffb     = (u16*)(uni + 4096ull * 1024 * 6);     // 4096x2816 bf16

  u16* wqkv_t = wqkvo_t;
  u16* wo_t   = wqkvo_t + 3ull * 1024 * 1024;
  u16* w1_t   = w13_t;
  u16* w3_t   = w13_t + 2816ull * 1024;

  k_tc4<<<dim3(32, 32, 4), 256, 0, stream>>>(wq, wk, wv, wo, wqkvo_t, 1024, 1024);
  k_tc4<<<dim3(88, 32, 2), 256, 0, stream>>>(w1, w3, w1, w3, w13_t, 1024, 2816);
  k_tc4<<<dim3(32, 88, 1), 256, 0, stream>>>(w2, w2, w2, w2, w2_t, 2816, 1024);

  k_rms<<<4096, 256, 0, stream>>>(x, ga, xn);
  k_gemm<0, 128><<<dim3(24, 32), 256, 0, stream>>>(xn, wqkv_t, qkvb, nullptr, nullptr, 4096, 3072, 1024);
  k_attn<<<512, 512, 0, stream>>>(qkvb, Opart, mlb);
  k_amerge<<<512, 256, 0, stream>>>(Opart, mlb, atn);
  k_gemm<1, 64><<<dim3(16, 32), 256, 0, stream>>>(atn, wo_t, nullptr, hb, x, 4096, 1024, 1024);
  k_rms<<<4096, 256, 0, stream>>>(hb, gf, hn);
  k_ffn13<<<dim3(44, 32), 256, 0, stream>>>(hn, w1_t, w3_t, ffb, 4096, 2816, 1024);
  k_gemm<1, 64><<<dim3(16, 32), 256, 0, stream>>>(ffb, w2_t, nullptr, out, hb, 4096, 1024, 2816);
}